// Round 1
// baseline (215.224 us; speedup 1.0000x reference)
//
#include <hip/hip_runtime.h>

// ---------------------------------------------------------------------------
// LoRA_Attention: fold LoRA into weights; bf16 MFMA GEMMs; split-K flash
// attention. R10: rws (relW stage) moved out of LDS to direct global bf16
// reads (k_relmm now emits relW as bf16) -> LDS 51712->38400 B -> 4 blk/CU
// (was 3; grid 864 > 768 capacity caused a 2-phase tail). rhs stays in LDS.
// __launch_bounds__(256,4) pins VGPR <= 128 so occupancy holds.
// exp2 softmax, no-max (scores bounded). XCD-swizzled attn grid.
// ---------------------------------------------------------------------------

#define DIM   768
#define HEADS 12
#define HD    64
#define NTOK  2304
#define RANK  8
#define GRD   48
#define CHUNKS 4
#define LOG2E 1.44269504088896f

typedef __attribute__((ext_vector_type(8))) short bf16x8;
typedef __attribute__((ext_vector_type(4))) float f32x4;
typedef unsigned short ushort_t;

__device__ __forceinline__ unsigned short f2bf(float x) {
    union { float f; unsigned u; } v; v.f = x;
    unsigned r = v.u + 0x7fffu + ((v.u >> 16) & 1u);
    return (unsigned short)(r >> 16);
}
__device__ __forceinline__ float bf2f(unsigned short h) {
    return __uint_as_float(((unsigned)h) << 16);
}
__device__ __forceinline__ void gload_lds16(const ushort_t* g, ushort_t* l) {
    __builtin_amdgcn_global_load_lds(
        (const __attribute__((address_space(1))) unsigned int*)g,
        (__attribute__((address_space(3))) unsigned int*)l, 16, 0, 0);
}

// ---------------------------------------------------------------------------
// k_prep: fold LoRA into transposed weights (all 2304 blocks) + convert
// x / rel tables to bf16 (blocks < 1740). Independent tasks, one launch.
// ---------------------------------------------------------------------------
__global__ __launch_bounds__(256) void k_prep(
    const float* __restrict__ x, ushort_t* __restrict__ xb,
    const float* __restrict__ rph, const float* __restrict__ rpw,
    ushort_t* __restrict__ rphb, ushort_t* __restrict__ rpwb,
    const float* __restrict__ Wq, const float* __restrict__ Wk,
    const float* __restrict__ Wv, const float* __restrict__ Wp,
    const float* __restrict__ Aq, const float* __restrict__ Bq,
    const float* __restrict__ Ak, const float* __restrict__ Bk,
    const float* __restrict__ Av, const float* __restrict__ Bv,
    ushort_t* __restrict__ WT) {
    int bid = blockIdx.x, tid = threadIdx.x;

    if (bid < 1740) {
        if (bid < 1728) {
            int idx = (bid * 256 + tid) * 4;
            float4 v = *(const float4*)(x + idx);
            ushort4 o = make_ushort4(f2bf(v.x), f2bf(v.y), f2bf(v.z), f2bf(v.w));
            *(ushort4*)(xb + idx) = o;
        } else {
            int e = ((bid - 1728) * 256 + tid) * 4;
            const int TSZ = (2 * GRD - 1) * HD;   // 6080
            if (e < TSZ) {
                float4 v = *(const float4*)(rph + e);
                ushort4 o = make_ushort4(f2bf(v.x), f2bf(v.y), f2bf(v.z), f2bf(v.w));
                *(ushort4*)(rphb + e) = o;
            } else if (e < 2 * TSZ) {
                float4 v = *(const float4*)(rpw + e - TSZ);
                ushort4 o = make_ushort4(f2bf(v.x), f2bf(v.y), f2bf(v.z), f2bf(v.w));
                *(ushort4*)(rpwb + e - TSZ) = o;
            }
        }
    }

    int kb = (bid % 24) * 32;
    int nb = (bid / 24) * 32;
    int sel = nb / DIM, nmod = nb % DIM;
    const float* W = (sel == 0) ? Wq : (sel == 1) ? Wk : (sel == 2) ? Wv : Wp;
    const float* A = (sel == 0) ? Aq : (sel == 1) ? Ak : Av;
    const float* B = (sel == 0) ? Bq : (sel == 1) ? Bk : Bv;
    __shared__ float T[32][33];
    for (int i = tid; i < 1024; i += 256) {
        int kl = i >> 5, nl = i & 31;
        float v = W[(kb + kl) * DIM + nmod + nl];
        if (sel < 3) {
            #pragma unroll
            for (int r = 0; r < RANK; r++)
                v += A[(kb + kl) * RANK + r] * B[r * DIM + nmod + nl];
        }
        T[kl][nl] = v;
    }
    __syncthreads();
    for (int i = tid; i < 1024; i += 256) {
        int nl = i >> 5, kl = i & 31;
        WT[(size_t)(nb + nl) * DIM + kb + kl] = f2bf(T[kl][nl]);
    }
}

// ---------------------------------------------------------------------------
// QKV GEMM: 128(M)x64(N) tiles -> 648 blocks (~2.5/CU, no packing tail),
// BK=32, global_load_lds DMA, 12 KB LDS. Waves 2x2: wave = 64 rows x 32 cols.
// ---------------------------------------------------------------------------
__global__ __launch_bounds__(256) void k_gemm_qkv(
    const ushort_t* __restrict__ xb, const ushort_t* __restrict__ WT,
    const float* __restrict__ bq, const float* __restrict__ bk,
    const float* __restrict__ bv,
    ushort_t* __restrict__ Qb, ushort_t* __restrict__ Kb,
    ushort_t* __restrict__ Vtb) {
    __shared__ __align__(16) ushort_t As[128 * 32];   // 8 KB
    __shared__ __align__(16) ushort_t Bs[64 * 32];    // 4 KB
    int tid = threadIdx.x;
    int wave = tid >> 6, lane = tid & 63, quad = lane >> 4, l16 = lane & 15;
    int wx = wave & 1, wy = wave >> 1;
    int nb = blockIdx.x * 64, mb = blockIdx.y * 128;

    f32x4 zero = {0.f, 0.f, 0.f, 0.f};
    f32x4 acc[4][2];
    #pragma unroll
    for (int i = 0; i < 4; i++)
        #pragma unroll
        for (int j = 0; j < 2; j++) acc[i][j] = zero;

    int rl = lane >> 2;            // 0..15
    int cl = (lane & 3) * 8;       // element col within 32
    const ushort_t* gA = xb + (size_t)(mb + wave * 32 + rl) * DIM + cl;
    const ushort_t* gB = WT + (size_t)(nb + wave * 16 + rl) * DIM + cl;
    ushort_t* lA = &As[(wave * 32) * 32];
    ushort_t* lB = &Bs[(wave * 16) * 32];

    for (int k0 = 0; k0 < DIM; k0 += 32) {
        __syncthreads();
        gload_lds16(gA + k0,            lA);
        gload_lds16(gA + k0 + 16 * DIM, lA + 16 * 32);
        gload_lds16(gB + k0,            lB);
        __syncthreads();
        bf16x8 af[4], bf[2];
        #pragma unroll
        for (int i = 0; i < 4; i++)
            af[i] = *(const bf16x8*)&As[(wy * 64 + i * 16 + l16) * 32 + quad * 8];
        #pragma unroll
        for (int j = 0; j < 2; j++)
            bf[j] = *(const bf16x8*)&Bs[(wx * 32 + j * 16 + l16) * 32 + quad * 8];
        #pragma unroll
        for (int i = 0; i < 4; i++)
            #pragma unroll
            for (int j = 0; j < 2; j++)
                acc[i][j] = __builtin_amdgcn_mfma_f32_16x16x32_bf16(af[i], bf[j], acc[i][j], 0, 0, 0);
    }

    #pragma unroll
    for (int j = 0; j < 2; j++) {
        int col = nb + wx * 32 + j * 16 + l16;
        int sel = col / DIM, rem = col % DIM;
        int hh = rem >> 6, cc = rem & 63;
        const float* bias = (sel == 0) ? bq : (sel == 1) ? bk : bv;
        float bval = bias[rem];
        #pragma unroll
        for (int i = 0; i < 4; i++) {
            #pragma unroll
            for (int r = 0; r < 4; r++) {
                int row = mb + wy * 64 + i * 16 + quad * 4 + r;
                unsigned short o = f2bf(acc[i][j][r] + bval);
                if (sel == 0)      Qb[(size_t)(hh * NTOK + row) * HD + cc] = o;
                else if (sel == 1) Kb[(size_t)(hh * NTOK + row) * HD + cc] = o;
                else               Vtb[(size_t)(hh * HD + cc) * NTOK + row] = o;
            }
        }
    }
}

// ---------------------------------------------------------------------------
// Rel-pos bias via MFMA (outputs pre-scaled by log2 e).
// relW now emitted as bf16 (k_attn reads it directly from global); relH
// stays f32 (staged+converted into k_attn's small rhs LDS buffer).
// ---------------------------------------------------------------------------
__global__ __launch_bounds__(256) void k_relmm(
    const ushort_t* __restrict__ Qb, const ushort_t* __restrict__ rphb,
    const ushort_t* __restrict__ rpwb, float* __restrict__ relH,
    ushort_t* __restrict__ relWb) {
    int id = blockIdx.x * 4 + (threadIdx.x >> 6);
    int lane = threadIdx.x & 63, quad = lane >> 4, l16 = lane & 15;
    bool isW = id >= 576;
    int t = isW ? id - 576 : id;
    int h = t / GRD, g = t % GRD;
    const ushort_t* tab = isW ? rpwb : rphb;

    f32x4 zero = {0.f, 0.f, 0.f, 0.f};
    f32x4 acc[3][3];
    #pragma unroll
    for (int i = 0; i < 3; i++)
        #pragma unroll
        for (int j = 0; j < 3; j++) acc[i][j] = zero;

    bf16x8 bfr[3][2];
    #pragma unroll
    for (int ct = 0; ct < 3; ct++) {
        int trow = g + 47 - (ct * 16 + l16);
        bfr[ct][0] = *(const bf16x8*)&tab[(size_t)trow * HD + quad * 8];
        bfr[ct][1] = *(const bf16x8*)&tab[(size_t)trow * HD + 32 + quad * 8];
    }
    #pragma unroll
    for (int ms = 0; ms < 3; ms++) {
        int m = ms * 16 + l16;
        int n = isW ? m * GRD + g : g * GRD + m;
        bf16x8 a0 = *(const bf16x8*)&Qb[(size_t)(h * NTOK + n) * HD + quad * 8];
        bf16x8 a1 = *(const bf16x8*)&Qb[(size_t)(h * NTOK + n) * HD + 32 + quad * 8];
        #pragma unroll
        for (int ct = 0; ct < 3; ct++) {
            acc[ms][ct] = __builtin_amdgcn_mfma_f32_16x16x32_bf16(a0, bfr[ct][0], acc[ms][ct], 0, 0, 0);
            acc[ms][ct] = __builtin_amdgcn_mfma_f32_16x16x32_bf16(a1, bfr[ct][1], acc[ms][ct], 0, 0, 0);
        }
    }
    #pragma unroll
    for (int ms = 0; ms < 3; ms++) {
        #pragma unroll
        for (int ct = 0; ct < 3; ct++) {
            #pragma unroll
            for (int r = 0; r < 4; r++) {
                int m = ms * 16 + quad * 4 + r;
                int n = isW ? m * GRD + g : g * GRD + m;
                int col = ct * 16 + l16;
                float val = acc[ms][ct][r] * LOG2E;
                if (isW)
                    relWb[(size_t)(h * NTOK + n) * GRD + col] = f2bf(val);
                else
                    relH[(size_t)(h * NTOK + n) * GRD + col] = val;
            }
        }
    }
}

// ---------------------------------------------------------------------------
// Flash attention, split-K. Block = (128 q-rows, head, chunk of 576 keys).
// Grid x = h*4+chunk (XCD-local K/V sharing). Coalesced uint4 reg-prefetch
// -> stride-68 LDS; S^T compute. R10: relW read directly from global as
// bf16 uint2 pairs (prefetched per kt-iteration, 8 loads in flight across
// the barrier pair) -> LDS 38400 B -> 4 blocks/CU, grid 864 <= 1024
// capacity: single-phase, tail eliminated. rhs (3.6 KB) stays in LDS.
// __launch_bounds__(256,4) pins VGPR <= 128 (4 waves/SIMD).
// ---------------------------------------------------------------------------
__global__ __launch_bounds__(256, 4) void k_attn(
    const ushort_t* __restrict__ Qb, const ushort_t* __restrict__ Kb,
    const ushort_t* __restrict__ Vtb, const float* __restrict__ relH,
    const ushort_t* __restrict__ relWb, float* __restrict__ Opart,
    float* __restrict__ Lpart) {
    int h = blockIdx.x >> 2, chunk = blockIdx.x & 3, qt = blockIdx.y;
    int tid = threadIdx.x;
    int wave = tid >> 6, lane = tid & 63, quad = lane >> 4, l16 = lane & 15;
    int qbase = qt * 128;
    int kbase = chunk * 576;

    __shared__ __align__(16) ushort_t Ks[64 * 68];
    __shared__ __align__(16) ushort_t Vs[64 * 68];
    __shared__ __align__(16) ushort_t Ps[4][32 * 68];
    __shared__ __align__(16) ushort_t rhs[128 * 14];

    for (int i = tid; i < 128 * 12; i += 256) {
        int r = i / 12, c = i % 12;
        rhs[r * 14 + c] = f2bf(relH[(size_t)(h * NTOK + qbase + r) * GRD + chunk * 12 + c]);
    }

    bf16x8 qf[2][2];
    #pragma unroll
    for (int s = 0; s < 2; s++) {
        int qrow = qbase + wave * 32 + s * 16 + l16;
        qf[s][0] = *(const bf16x8*)&Qb[(size_t)(h * NTOK + qrow) * HD + quad * 8];
        qf[s][1] = *(const bf16x8*)&Qb[(size_t)(h * NTOK + qrow) * HD + 32 + quad * 8];
    }

    int r0 = tid >> 3, c0 = (tid & 7) * 8;
    const ushort_t* kg0 = Kb + (size_t)(h * NTOK + r0) * HD + c0;
    const ushort_t* kg1 = Kb + (size_t)(h * NTOK + r0 + 32) * HD + c0;
    const ushort_t* vg0 = Vtb + (size_t)(h * HD + r0) * NTOK + c0;
    const ushort_t* vg1 = Vtb + (size_t)(h * HD + r0 + 32) * NTOK + c0;
    int sk0 = r0 * 68 + c0, sk1 = sk0 + 32 * 68;

    // per-lane relW row pointers (rows owned by this lane across s=0,1)
    const ushort_t* rw0 = relWb + (size_t)(h * NTOK + qbase + wave * 32 + l16) * GRD;
    const ushort_t* rw1 = rw0 + (size_t)16 * GRD;

    float lacc[2] = {0.f, 0.f};
    f32x4 zero = {0.f, 0.f, 0.f, 0.f};
    f32x4 oacc[2][4];
    #pragma unroll
    for (int s = 0; s < 2; s++)
        #pragma unroll
        for (int cs = 0; cs < 4; cs++) oacc[s][cs] = zero;

    const float scale2 = 0.125f * LOG2E;

    uint4 rk0 = *(const uint4*)(kg0 + (size_t)kbase * HD);
    uint4 rk1 = *(const uint4*)(kg1 + (size_t)kbase * HD);
    uint4 rv0 = *(const uint4*)(vg0 + kbase);
    uint4 rv1 = *(const uint4*)(vg1 + kbase);

    for (int kt = 0; kt < 9; kt++) {
        int kb = kbase + kt * 64;

        // prefetch this iteration's relW bias (8B per (s,ks)); issued before
        // the barrier pair so the L2 latency hides under K/V staging + S-MFMA
        uint2 rwv[2][4];
        #pragma unroll
        for (int ks = 0; ks < 4; ks++) {
            int kb4 = kb + ks * 16 + quad * 4;
            int kh = kb4 / 48;
            int kw0 = kb4 - kh * 48;
            rwv[0][ks] = *(const uint2*)(rw0 + kw0);
            rwv[1][ks] = *(const uint2*)(rw1 + kw0);
        }

        __syncthreads();
        *(uint4*)&Ks[sk0] = rk0;  *(uint4*)&Ks[sk1] = rk1;
        *(uint4*)&Vs[sk0] = rv0;  *(uint4*)&Vs[sk1] = rv1;
        __syncthreads();
        if (kt < 8) {
            int kbn = kb + 64;
            rk0 = *(const uint4*)(kg0 + (size_t)kbn * HD);
            rk1 = *(const uint4*)(kg1 + (size_t)kbn * HD);
            rv0 = *(const uint4*)(vg0 + kbn);
            rv1 = *(const uint4*)(vg1 + kbn);
        }

        #pragma unroll
        for (int ks = 0; ks < 4; ks++) {
            bf16x8 kf0 = *(const bf16x8*)&Ks[(ks * 16 + l16) * 68 + quad * 8];
            bf16x8 kf1 = *(const bf16x8*)&Ks[(ks * 16 + l16) * 68 + 32 + quad * 8];
            f32x4 st[2];
            #pragma unroll
            for (int s = 0; s < 2; s++) {
                f32x4 z = zero;
                z = __builtin_amdgcn_mfma_f32_16x16x32_bf16(kf0, qf[s][0], z, 0, 0, 0);
                z = __builtin_amdgcn_mfma_f32_16x16x32_bf16(kf1, qf[s][1], z, 0, 0, 0);
                st[s] = z;
            }
            int kb4 = kb + ks * 16 + quad * 4;
            int khl = kb4 / 48 - chunk * 12;
            #pragma unroll
            for (int s = 0; s < 2; s++) {
                int row = wave * 32 + s * 16 + l16;
                float rh = bf2f(rhs[row * 14 + khl]);
                uint2 u = rwv[s][ks];
                float p0 = __builtin_amdgcn_exp2f(st[s][0] * scale2 + rh + __uint_as_float(u.x << 16));
                float p1 = __builtin_amdgcn_exp2f(st[s][1] * scale2 + rh + __uint_as_float(u.x & 0xffff0000u));
                float p2 = __builtin_amdgcn_exp2f(st[s][2] * scale2 + rh + __uint_as_float(u.y << 16));
                float p3 = __builtin_amdgcn_exp2f(st[s][3] * scale2 + rh + __uint_as_float(u.y & 0xffff0000u));
                lacc[s] += (p0 + p1) + (p2 + p3);
                uint2 w;
                w.x = __builtin_amdgcn_perm(__float_as_uint(p1), __float_as_uint(p0), 0x07060302u);
                w.y = __builtin_amdgcn_perm(__float_as_uint(p3), __float_as_uint(p2), 0x07060302u);
                *(uint2*)&Ps[wave][(s * 16 + l16) * 68 + ks * 16 + quad * 4] = w;
            }
        }

        bf16x8 vf[4][2];
        #pragma unroll
        for (int cs = 0; cs < 4; cs++) {
            vf[cs][0] = *(const bf16x8*)&Vs[(cs * 16 + l16) * 68 + quad * 8];
            vf[cs][1] = *(const bf16x8*)&Vs[(cs * 16 + l16) * 68 + 32 + quad * 8];
        }
        #pragma unroll
        for (int s = 0; s < 2; s++) {
            bf16x8 pa0 = *(const bf16x8*)&Ps[wave][(s * 16 + l16) * 68 + quad * 8];
            bf16x8 pa1 = *(const bf16x8*)&Ps[wave][(s * 16 + l16) * 68 + 32 + quad * 8];
            #pragma unroll
            for (int cs = 0; cs < 4; cs++) {
                oacc[s][cs] = __builtin_amdgcn_mfma_f32_16x16x32_bf16(pa0, vf[cs][0], oacc[s][cs], 0, 0, 0);
                oacc[s][cs] = __builtin_amdgcn_mfma_f32_16x16x32_bf16(pa1, vf[cs][1], oacc[s][cs], 0, 0, 0);
            }
        }
    }

    #pragma unroll
    for (int s = 0; s < 2; s++) {
        float l = lacc[s];
        l += __shfl_xor(l, 16);
        l += __shfl_xor(l, 32);
        lacc[s] = l;
    }

    size_t obase = (size_t)(chunk * HEADS + h) * NTOK;
    #pragma unroll
    for (int s = 0; s < 2; s++) {
        #pragma unroll
        for (int cs = 0; cs < 4; cs++) {
            #pragma unroll
            for (int r = 0; r < 4; r++) {
                int row = qbase + wave * 32 + s * 16 + quad * 4 + r;
                Opart[(obase + row) * HD + cs * 16 + l16] = oacc[s][cs][r];
            }
        }
        if (quad == 0)
            Lpart[obase + qbase + wave * 32 + s * 16 + l16] = lacc[s];
    }
}

// ---------------------------------------------------------------------------
// Merge split-K partials: Ob = (sum_ch O) / (sum_ch l), bf16.
// ---------------------------------------------------------------------------
__global__ __launch_bounds__(256) void k_merge(const float* __restrict__ Opart,
                                               const float* __restrict__ Lpart,
                                               ushort_t* __restrict__ Ob) {
    int t = blockIdx.x * 256 + threadIdx.x;
    int e = t * 4;
    int c = e & (HD - 1);
    int row = (e >> 6) % NTOK;
    int h = e / (NTOK * HD);
    const int ostride = HEADS * NTOK * HD;
    float4 s = {0.f, 0.f, 0.f, 0.f};
    float l = 0.f;
    #pragma unroll
    for (int ch = 0; ch < CHUNKS; ch++) {
        float4 v = *(const float4*)&Opart[(size_t)ch * ostride + e];
        s.x += v.x; s.y += v.y; s.z += v.z; s.w += v.w;
        l += Lpart[(size_t)(ch * HEADS + h) * NTOK + row];
    }
    float inv = 1.0f / l;
    ushort4 o = make_ushort4(f2bf(s.x * inv), f2bf(s.y * inv),
                             f2bf(s.z * inv), f2bf(s.w * inv));
    *(ushort4*)&Ob[(size_t)row * DIM + h * HD + c] = o;
}

// ---------------------------------------------------------------------------
// Output projection: 128(M)x64(N) tiles -> 216 blocks, BK=32,
// global_load_lds DMA staging, 12 KB LDS. 2x2 waves: wave = 64 rows x 32 cols.
// ---------------------------------------------------------------------------
__global__ __launch_bounds__(256) void k_gemm_proj(
    const ushort_t* __restrict__ Ob, const ushort_t* __restrict__ WTp,
    const float* __restrict__ bp, float* __restrict__ out) {
    __shared__ __align__(16) ushort_t As[128 * 32];   // 8 KB
    __shared__ __align__(16) ushort_t Bs[64 * 32];    // 4 KB
    int tid = threadIdx.x;
    int wave = tid >> 6, lane = tid & 63, quad = lane >> 4, l16 = lane & 15;
    int wx = wave & 1, wy = wave >> 1;
    int nb = blockIdx.x * 64, mb = blockIdx.y * 128;

    f32x4 zero = {0.f, 0.f, 0.f, 0.f};
    f32x4 acc[4][2];
    #pragma unroll
    for (int i = 0; i < 4; i++)
        #pragma unroll
        for (int j = 0; j < 2; j++) acc[i][j] = zero;

    int rl = lane >> 2;
    int cl = (lane & 3) * 8;
    const ushort_t* gA = Ob + (size_t)(mb + wave * 32 + rl) * DIM + cl;
    const ushort_t* gB = WTp + (size_t)(nb + wave * 16 + rl) * DIM + cl;
    ushort_t* lA = &As[(wave * 32) * 32];
    ushort_t* lB = &Bs[(wave * 16) * 32];

    for (int k0 = 0; k0 < DIM; k0 += 32) {
        __syncthreads();
        gload_lds16(gA + k0,            lA);
        gload_lds16(gA + k0 + 16 * DIM, lA + 16 * 32);
        gload_lds16(gB + k0,            lB);
        __syncthreads();
        bf16x8 af[4], bf[2];
        #pragma unroll
        for (int i = 0; i < 4; i++)
            af[i] = *(const bf16x8*)&As[(wy * 64 + i * 16 + l16) * 32 + quad * 8];
        #pragma unroll
        for (int j = 0; j < 2; j++)
            bf[j] = *(const bf16x8*)&Bs[(wx * 32 + j * 16 + l16) * 32 + quad * 8];
        #pragma unroll
        for (int i = 0; i < 4; i++)
            #pragma unroll
            for (int j = 0; j < 2; j++)
                acc[i][j] = __builtin_amdgcn_mfma_f32_16x16x32_bf16(af[i], bf[j], acc[i][j], 0, 0, 0);
    }

    #pragma unroll
    for (int j = 0; j < 2; j++) {
        int col = nb + wx * 32 + j * 16 + l16;
        float bval = bp[col];
        #pragma unroll
        for (int i = 0; i < 4; i++) {
            #pragma unroll
            for (int r = 0; r < 4; r++) {
                int row = mb + wy * 64 + i * 16 + quad * 4 + r;
                out[(size_t)row * DIM + col] = acc[i][j][r] + bval;
            }
        }
    }
}

// ---------------------------------------------------------------------------
extern "C" void kernel_launch(void* const* d_in, const int* in_sizes, int n_in,
                              void* d_out, int out_size, void* d_ws, size_t ws_size,
                              hipStream_t stream) {
    const float* x   = (const float*)d_in[0];
    const float* Wq  = (const float*)d_in[1];
    const float* bq  = (const float*)d_in[2];
    const float* Wk  = (const float*)d_in[3];
    const float* bk  = (const float*)d_in[4];
    const float* Wv  = (const float*)d_in[5];
    const float* bv  = (const float*)d_in[6];
    const float* Wp  = (const float*)d_in[7];
    const float* bp  = (const float*)d_in[8];
    const float* rph = (const float*)d_in[9];
    const float* rpw = (const float*)d_in[10];
    const float* Aq  = (const float*)d_in[11];
    const float* Bq  = (const float*)d_in[12];
    const float* Ak  = (const float*)d_in[13];
    const float* Bk  = (const float*)d_in[14];
    const float* Av  = (const float*)d_in[15];
    const float* Bv  = (const float*)d_in[16];
    float* out = (float*)d_out;

    char* w = (char*)d_ws;
    size_t off = 0;
    auto carve = [&](size_t bytes) {
        char* p = w + off;
        off += (bytes + 255) & ~(size_t)255;
        return p;
    };
    ushort_t* xb    = (ushort_t*)carve((size_t)NTOK * DIM * 2);
    ushort_t* WT    = (ushort_t*)carve((size_t)4 * DIM * DIM * 2);
    ushort_t* Qb    = (ushort_t*)carve((size_t)HEADS * NTOK * HD * 2);
    ushort_t* Kb    = (ushort_t*)carve((size_t)HEADS * NTOK * HD * 2);
    ushort_t* Vtb   = (ushort_t*)carve((size_t)HEADS * HD * NTOK * 2);
    float*    relH  = (float*)carve((size_t)HEADS * NTOK * GRD * 4);
    ushort_t* relWb = (ushort_t*)carve((size_t)HEADS * NTOK * GRD * 2);
    ushort_t* Ob    = (ushort_t*)carve((size_t)NTOK * DIM * 2);
    float*    Opart = (float*)carve((size_t)CHUNKS * HEADS * NTOK * HD * 4);
    float*    Lpart = (float*)carve((size_t)CHUNKS * HEADS * NTOK * 4);
    ushort_t* rphb  = (ushort_t*)carve((size_t)(2 * GRD - 1) * HD * 2);
    ushort_t* rpwb  = (ushort_t*)carve((size_t)(2 * GRD - 1) * HD * 2);

    k_prep<<<dim3(2304), dim3(256), 0, stream>>>(
        x, xb, rph, rpw, rphb, rpwb,
        Wq, Wk, Wv, Wp, Aq, Bq, Ak, Bk, Av, Bv, WT);
    k_gemm_qkv<<<dim3(36, 18), dim3(256), 0, stream>>>(
        xb, WT, bq, bk, bv, Qb, Kb, Vtb);
    k_relmm<<<dim3(288), dim3(256), 0, stream>>>(
        Qb, rphb, rpwb, relH, relWb);
    k_attn<<<dim3(HEADS * CHUNKS, NTOK / 128), dim3(256), 0, stream>>>(
        Qb, Kb, Vtb, relH, relWb, Opart, Lpart);
    k_merge<<<dim3(HEADS * NTOK * HD / (256 * 4)), dim3(256), 0, stream>>>(
        Opart, Lpart, Ob);
    k_gemm_proj<<<dim3(12, 18), dim3(256), 0, stream>>>(
        Ob, WT + (size_t)3 * DIM * DIM, bp, out);
}

// Round 3
// 196.521 us; speedup vs baseline: 1.0952x; 1.0952x over previous
//
#include <hip/hip_runtime.h>

// ---------------------------------------------------------------------------
// LoRA_Attention: fold LoRA into weights; bf16 MFMA GEMMs; split-K flash
// attention. R11: relW read direct from global bf16 (LDS 38400 -> 4 blk/CU,
// single-phase grid 864<=1024); k_attn uses PLAIN __launch_bounds__(256) —
// the (256,4) min-waves pin made LLVM chase the 64-VGPR/8-wave tier and
// spill (R10: WRITE_SIZE +24MB = scratch). LDS already implies the 4-wave
// budget (128 VGPR); default allocator lands ~124, no spill.
// exp2 softmax, no-max (scores bounded). XCD-swizzled attn grid.
// ---------------------------------------------------------------------------

#define DIM   768
#define HEADS 12
#define HD    64
#define NTOK  2304
#define RANK  8
#define GRD   48
#define CHUNKS 4
#define LOG2E 1.44269504088896f

typedef __attribute__((ext_vector_type(8))) short bf16x8;
typedef __attribute__((ext_vector_type(4))) float f32x4;
typedef unsigned short ushort_t;

__device__ __forceinline__ unsigned short f2bf(float x) {
    union { float f; unsigned u; } v; v.f = x;
    unsigned r = v.u + 0x7fffu + ((v.u >> 16) & 1u);
    return (unsigned short)(r >> 16);
}
__device__ __forceinline__ float bf2f(unsigned short h) {
    return __uint_as_float(((unsigned)h) << 16);
}
__device__ __forceinline__ void gload_lds16(const ushort_t* g, ushort_t* l) {
    __builtin_amdgcn_global_load_lds(
        (const __attribute__((address_space(1))) unsigned int*)g,
        (__attribute__((address_space(3))) unsigned int*)l, 16, 0, 0);
}

// ---------------------------------------------------------------------------
// k_prep: fold LoRA into transposed weights (all 2304 blocks) + convert
// x / rel tables to bf16 (blocks < 1740). Independent tasks, one launch.
// ---------------------------------------------------------------------------
__global__ __launch_bounds__(256) void k_prep(
    const float* __restrict__ x, ushort_t* __restrict__ xb,
    const float* __restrict__ rph, const float* __restrict__ rpw,
    ushort_t* __restrict__ rphb, ushort_t* __restrict__ rpwb,
    const float* __restrict__ Wq, const float* __restrict__ Wk,
    const float* __restrict__ Wv, const float* __restrict__ Wp,
    const float* __restrict__ Aq, const float* __restrict__ Bq,
    const float* __restrict__ Ak, const float* __restrict__ Bk,
    const float* __restrict__ Av, const float* __restrict__ Bv,
    ushort_t* __restrict__ WT) {
    int bid = blockIdx.x, tid = threadIdx.x;

    if (bid < 1740) {
        if (bid < 1728) {
            int idx = (bid * 256 + tid) * 4;
            float4 v = *(const float4*)(x + idx);
            ushort4 o = make_ushort4(f2bf(v.x), f2bf(v.y), f2bf(v.z), f2bf(v.w));
            *(ushort4*)(xb + idx) = o;
        } else {
            int e = ((bid - 1728) * 256 + tid) * 4;
            const int TSZ = (2 * GRD - 1) * HD;   // 6080
            if (e < TSZ) {
                float4 v = *(const float4*)(rph + e);
                ushort4 o = make_ushort4(f2bf(v.x), f2bf(v.y), f2bf(v.z), f2bf(v.w));
                *(ushort4*)(rphb + e) = o;
            } else if (e < 2 * TSZ) {
                float4 v = *(const float4*)(rpw + e - TSZ);
                ushort4 o = make_ushort4(f2bf(v.x), f2bf(v.y), f2bf(v.z), f2bf(v.w));
                *(ushort4*)(rpwb + e - TSZ) = o;
            }
        }
    }

    int kb = (bid % 24) * 32;
    int nb = (bid / 24) * 32;
    int sel = nb / DIM, nmod = nb % DIM;
    const float* W = (sel == 0) ? Wq : (sel == 1) ? Wk : (sel == 2) ? Wv : Wp;
    const float* A = (sel == 0) ? Aq : (sel == 1) ? Ak : Av;
    const float* B = (sel == 0) ? Bq : (sel == 1) ? Bk : Bv;
    __shared__ float T[32][33];
    for (int i = tid; i < 1024; i += 256) {
        int kl = i >> 5, nl = i & 31;
        float v = W[(kb + kl) * DIM + nmod + nl];
        if (sel < 3) {
            #pragma unroll
            for (int r = 0; r < RANK; r++)
                v += A[(kb + kl) * RANK + r] * B[r * DIM + nmod + nl];
        }
        T[kl][nl] = v;
    }
    __syncthreads();
    for (int i = tid; i < 1024; i += 256) {
        int nl = i >> 5, kl = i & 31;
        WT[(size_t)(nb + nl) * DIM + kb + kl] = f2bf(T[kl][nl]);
    }
}

// ---------------------------------------------------------------------------
// QKV GEMM: 128(M)x64(N) tiles -> 648 blocks (~2.5/CU, no packing tail),
// BK=32, global_load_lds DMA, 12 KB LDS. Waves 2x2: wave = 64 rows x 32 cols.
// ---------------------------------------------------------------------------
__global__ __launch_bounds__(256) void k_gemm_qkv(
    const ushort_t* __restrict__ xb, const ushort_t* __restrict__ WT,
    const float* __restrict__ bq, const float* __restrict__ bk,
    const float* __restrict__ bv,
    ushort_t* __restrict__ Qb, ushort_t* __restrict__ Kb,
    ushort_t* __restrict__ Vtb) {
    __shared__ __align__(16) ushort_t As[128 * 32];   // 8 KB
    __shared__ __align__(16) ushort_t Bs[64 * 32];    // 4 KB
    int tid = threadIdx.x;
    int wave = tid >> 6, lane = tid & 63, quad = lane >> 4, l16 = lane & 15;
    int wx = wave & 1, wy = wave >> 1;
    int nb = blockIdx.x * 64, mb = blockIdx.y * 128;

    f32x4 zero = {0.f, 0.f, 0.f, 0.f};
    f32x4 acc[4][2];
    #pragma unroll
    for (int i = 0; i < 4; i++)
        #pragma unroll
        for (int j = 0; j < 2; j++) acc[i][j] = zero;

    int rl = lane >> 2;            // 0..15
    int cl = (lane & 3) * 8;       // element col within 32
    const ushort_t* gA = xb + (size_t)(mb + wave * 32 + rl) * DIM + cl;
    const ushort_t* gB = WT + (size_t)(nb + wave * 16 + rl) * DIM + cl;
    ushort_t* lA = &As[(wave * 32) * 32];
    ushort_t* lB = &Bs[(wave * 16) * 32];

    for (int k0 = 0; k0 < DIM; k0 += 32) {
        __syncthreads();
        gload_lds16(gA + k0,            lA);
        gload_lds16(gA + k0 + 16 * DIM, lA + 16 * 32);
        gload_lds16(gB + k0,            lB);
        __syncthreads();
        bf16x8 af[4], bf[2];
        #pragma unroll
        for (int i = 0; i < 4; i++)
            af[i] = *(const bf16x8*)&As[(wy * 64 + i * 16 + l16) * 32 + quad * 8];
        #pragma unroll
        for (int j = 0; j < 2; j++)
            bf[j] = *(const bf16x8*)&Bs[(wx * 32 + j * 16 + l16) * 32 + quad * 8];
        #pragma unroll
        for (int i = 0; i < 4; i++)
            #pragma unroll
            for (int j = 0; j < 2; j++)
                acc[i][j] = __builtin_amdgcn_mfma_f32_16x16x32_bf16(af[i], bf[j], acc[i][j], 0, 0, 0);
    }

    #pragma unroll
    for (int j = 0; j < 2; j++) {
        int col = nb + wx * 32 + j * 16 + l16;
        int sel = col / DIM, rem = col % DIM;
        int hh = rem >> 6, cc = rem & 63;
        const float* bias = (sel == 0) ? bq : (sel == 1) ? bk : bv;
        float bval = bias[rem];
        #pragma unroll
        for (int i = 0; i < 4; i++) {
            #pragma unroll
            for (int r = 0; r < 4; r++) {
                int row = mb + wy * 64 + i * 16 + quad * 4 + r;
                unsigned short o = f2bf(acc[i][j][r] + bval);
                if (sel == 0)      Qb[(size_t)(hh * NTOK + row) * HD + cc] = o;
                else if (sel == 1) Kb[(size_t)(hh * NTOK + row) * HD + cc] = o;
                else               Vtb[(size_t)(hh * HD + cc) * NTOK + row] = o;
            }
        }
    }
}

// ---------------------------------------------------------------------------
// Rel-pos bias via MFMA (outputs pre-scaled by log2 e).
// relW emitted as bf16 (k_attn reads it directly from global); relH
// stays f32 (staged+converted into k_attn's small rhs LDS buffer).
// ---------------------------------------------------------------------------
__global__ __launch_bounds__(256) void k_relmm(
    const ushort_t* __restrict__ Qb, const ushort_t* __restrict__ rphb,
    const ushort_t* __restrict__ rpwb, float* __restrict__ relH,
    ushort_t* __restrict__ relWb) {
    int id = blockIdx.x * 4 + (threadIdx.x >> 6);
    int lane = threadIdx.x & 63, quad = lane >> 4, l16 = lane & 15;
    bool isW = id >= 576;
    int t = isW ? id - 576 : id;
    int h = t / GRD, g = t % GRD;
    const ushort_t* tab = isW ? rpwb : rphb;

    f32x4 zero = {0.f, 0.f, 0.f, 0.f};
    f32x4 acc[3][3];
    #pragma unroll
    for (int i = 0; i < 3; i++)
        #pragma unroll
        for (int j = 0; j < 3; j++) acc[i][j] = zero;

    bf16x8 bfr[3][2];
    #pragma unroll
    for (int ct = 0; ct < 3; ct++) {
        int trow = g + 47 - (ct * 16 + l16);
        bfr[ct][0] = *(const bf16x8*)&tab[(size_t)trow * HD + quad * 8];
        bfr[ct][1] = *(const bf16x8*)&tab[(size_t)trow * HD + 32 + quad * 8];
    }
    #pragma unroll
    for (int ms = 0; ms < 3; ms++) {
        int m = ms * 16 + l16;
        int n = isW ? m * GRD + g : g * GRD + m;
        bf16x8 a0 = *(const bf16x8*)&Qb[(size_t)(h * NTOK + n) * HD + quad * 8];
        bf16x8 a1 = *(const bf16x8*)&Qb[(size_t)(h * NTOK + n) * HD + 32 + quad * 8];
        #pragma unroll
        for (int ct = 0; ct < 3; ct++) {
            acc[ms][ct] = __builtin_amdgcn_mfma_f32_16x16x32_bf16(a0, bfr[ct][0], acc[ms][ct], 0, 0, 0);
            acc[ms][ct] = __builtin_amdgcn_mfma_f32_16x16x32_bf16(a1, bfr[ct][1], acc[ms][ct], 0, 0, 0);
        }
    }
    #pragma unroll
    for (int ms = 0; ms < 3; ms++) {
        #pragma unroll
        for (int ct = 0; ct < 3; ct++) {
            #pragma unroll
            for (int r = 0; r < 4; r++) {
                int m = ms * 16 + quad * 4 + r;
                int n = isW ? m * GRD + g : g * GRD + m;
                int col = ct * 16 + l16;
                float val = acc[ms][ct][r] * LOG2E;
                if (isW)
                    relWb[(size_t)(h * NTOK + n) * GRD + col] = f2bf(val);
                else
                    relH[(size_t)(h * NTOK + n) * GRD + col] = val;
            }
        }
    }
}

// ---------------------------------------------------------------------------
// Flash attention, split-K. Block = (128 q-rows, head, chunk of 576 keys).
// Grid x = h*4+chunk (XCD-local K/V sharing). Coalesced uint4 reg-prefetch
// -> stride-68 LDS; S^T compute. relW read directly from global as bf16
// uint2 pairs (prefetched per kt-iteration) -> LDS 38400 B -> 4 blocks/CU,
// grid 864 <= 1024 capacity: single-phase. rhs (3.6 KB) stays in LDS.
// PLAIN launch_bounds(256): LDS implies 4-wave/EU budget (128 VGPR);
// the explicit (256,4) pin made LLVM spill chasing 64 VGPR (R10).
// ---------------------------------------------------------------------------
__global__ __launch_bounds__(256) void k_attn(
    const ushort_t* __restrict__ Qb, const ushort_t* __restrict__ Kb,
    const ushort_t* __restrict__ Vtb, const float* __restrict__ relH,
    const ushort_t* __restrict__ relWb, float* __restrict__ Opart,
    float* __restrict__ Lpart) {
    int h = blockIdx.x >> 2, chunk = blockIdx.x & 3, qt = blockIdx.y;
    int tid = threadIdx.x;
    int wave = tid >> 6, lane = tid & 63, quad = lane >> 4, l16 = lane & 15;
    int qbase = qt * 128;
    int kbase = chunk * 576;

    __shared__ __align__(16) ushort_t Ks[64 * 68];
    __shared__ __align__(16) ushort_t Vs[64 * 68];
    __shared__ __align__(16) ushort_t Ps[4][32 * 68];
    __shared__ __align__(16) ushort_t rhs[128 * 14];

    for (int i = tid; i < 128 * 12; i += 256) {
        int r = i / 12, c = i % 12;
        rhs[r * 14 + c] = f2bf(relH[(size_t)(h * NTOK + qbase + r) * GRD + chunk * 12 + c]);
    }

    bf16x8 qf[2][2];
    #pragma unroll
    for (int s = 0; s < 2; s++) {
        int qrow = qbase + wave * 32 + s * 16 + l16;
        qf[s][0] = *(const bf16x8*)&Qb[(size_t)(h * NTOK + qrow) * HD + quad * 8];
        qf[s][1] = *(const bf16x8*)&Qb[(size_t)(h * NTOK + qrow) * HD + 32 + quad * 8];
    }

    int r0 = tid >> 3, c0 = (tid & 7) * 8;
    const ushort_t* kg0 = Kb + (size_t)(h * NTOK + r0) * HD + c0;
    const ushort_t* kg1 = Kb + (size_t)(h * NTOK + r0 + 32) * HD + c0;
    const ushort_t* vg0 = Vtb + (size_t)(h * HD + r0) * NTOK + c0;
    const ushort_t* vg1 = Vtb + (size_t)(h * HD + r0 + 32) * NTOK + c0;
    int sk0 = r0 * 68 + c0, sk1 = sk0 + 32 * 68;

    // per-lane relW row pointers (rows owned by this lane across s=0,1)
    const ushort_t* rw0 = relWb + (size_t)(h * NTOK + qbase + wave * 32 + l16) * GRD;
    const ushort_t* rw1 = rw0 + (size_t)16 * GRD;

    float lacc[2] = {0.f, 0.f};
    f32x4 zero = {0.f, 0.f, 0.f, 0.f};
    f32x4 oacc[2][4];
    #pragma unroll
    for (int s = 0; s < 2; s++)
        #pragma unroll
        for (int cs = 0; cs < 4; cs++) oacc[s][cs] = zero;

    const float scale2 = 0.125f * LOG2E;

    uint4 rk0 = *(const uint4*)(kg0 + (size_t)kbase * HD);
    uint4 rk1 = *(const uint4*)(kg1 + (size_t)kbase * HD);
    uint4 rv0 = *(const uint4*)(vg0 + kbase);
    uint4 rv1 = *(const uint4*)(vg1 + kbase);

    for (int kt = 0; kt < 9; kt++) {
        int kb = kbase + kt * 64;

        // prefetch this iteration's relW bias (8B per (s,ks)); issued before
        // the barrier pair so the L2 latency hides under K/V staging + S-MFMA
        uint2 rwv[2][4];
        #pragma unroll
        for (int ks = 0; ks < 4; ks++) {
            int kb4 = kb + ks * 16 + quad * 4;
            int kh = kb4 / 48;
            int kw0 = kb4 - kh * 48;
            rwv[0][ks] = *(const uint2*)(rw0 + kw0);
            rwv[1][ks] = *(const uint2*)(rw1 + kw0);
        }

        __syncthreads();
        *(uint4*)&Ks[sk0] = rk0;  *(uint4*)&Ks[sk1] = rk1;
        *(uint4*)&Vs[sk0] = rv0;  *(uint4*)&Vs[sk1] = rv1;
        __syncthreads();
        if (kt < 8) {
            int kbn = kb + 64;
            rk0 = *(const uint4*)(kg0 + (size_t)kbn * HD);
            rk1 = *(const uint4*)(kg1 + (size_t)kbn * HD);
            rv0 = *(const uint4*)(vg0 + kbn);
            rv1 = *(const uint4*)(vg1 + kbn);
        }

        #pragma unroll
        for (int ks = 0; ks < 4; ks++) {
            bf16x8 kf0 = *(const bf16x8*)&Ks[(ks * 16 + l16) * 68 + quad * 8];
            bf16x8 kf1 = *(const bf16x8*)&Ks[(ks * 16 + l16) * 68 + 32 + quad * 8];
            f32x4 st[2];
            #pragma unroll
            for (int s = 0; s < 2; s++) {
                f32x4 z = zero;
                z = __builtin_amdgcn_mfma_f32_16x16x32_bf16(kf0, qf[s][0], z, 0, 0, 0);
                z = __builtin_amdgcn_mfma_f32_16x16x32_bf16(kf1, qf[s][1], z, 0, 0, 0);
                st[s] = z;
            }
            int kb4 = kb + ks * 16 + quad * 4;
            int khl = kb4 / 48 - chunk * 12;
            #pragma unroll
            for (int s = 0; s < 2; s++) {
                int row = wave * 32 + s * 16 + l16;
                float rh = bf2f(rhs[row * 14 + khl]);
                uint2 u = rwv[s][ks];
                float p0 = __builtin_amdgcn_exp2f(st[s][0] * scale2 + rh + __uint_as_float(u.x << 16));
                float p1 = __builtin_amdgcn_exp2f(st[s][1] * scale2 + rh + __uint_as_float(u.x & 0xffff0000u));
                float p2 = __builtin_amdgcn_exp2f(st[s][2] * scale2 + rh + __uint_as_float(u.y << 16));
                float p3 = __builtin_amdgcn_exp2f(st[s][3] * scale2 + rh + __uint_as_float(u.y & 0xffff0000u));
                lacc[s] += (p0 + p1) + (p2 + p3);
                uint2 w;
                w.x = __builtin_amdgcn_perm(__float_as_uint(p1), __float_as_uint(p0), 0x07060302u);
                w.y = __builtin_amdgcn_perm(__float_as_uint(p3), __float_as_uint(p2), 0x07060302u);
                *(uint2*)&Ps[wave][(s * 16 + l16) * 68 + ks * 16 + quad * 4] = w;
            }
        }

        bf16x8 vf[4][2];
        #pragma unroll
        for (int cs = 0; cs < 4; cs++) {
            vf[cs][0] = *(const bf16x8*)&Vs[(cs * 16 + l16) * 68 + quad * 8];
            vf[cs][1] = *(const bf16x8*)&Vs[(cs * 16 + l16) * 68 + 32 + quad * 8];
        }
        #pragma unroll
        for (int s = 0; s < 2; s++) {
            bf16x8 pa0 = *(const bf16x8*)&Ps[wave][(s * 16 + l16) * 68 + quad * 8];
            bf16x8 pa1 = *(const bf16x8*)&Ps[wave][(s * 16 + l16) * 68 + 32 + quad * 8];
            #pragma unroll
            for (int cs = 0; cs < 4; cs++) {
                oacc[s][cs] = __builtin_amdgcn_mfma_f32_16x16x32_bf16(pa0, vf[cs][0], oacc[s][cs], 0, 0, 0);
                oacc[s][cs] = __builtin_amdgcn_mfma_f32_16x16x32_bf16(pa1, vf[cs][1], oacc[s][cs], 0, 0, 0);
            }
        }
    }

    #pragma unroll
    for (int s = 0; s < 2; s++) {
        float l = lacc[s];
        l += __shfl_xor(l, 16);
        l += __shfl_xor(l, 32);
        lacc[s] = l;
    }

    size_t obase = (size_t)(chunk * HEADS + h) * NTOK;
    #pragma unroll
    for (int s = 0; s < 2; s++) {
        #pragma unroll
        for (int cs = 0; cs < 4; cs++) {
            #pragma unroll
            for (int r = 0; r < 4; r++) {
                int row = qbase + wave * 32 + s * 16 + quad * 4 + r;
                Opart[(obase + row) * HD + cs * 16 + l16] = oacc[s][cs][r];
            }
        }
        if (quad == 0)
            Lpart[obase + qbase + wave * 32 + s * 16 + l16] = lacc[s];
    }
}

// ---------------------------------------------------------------------------
// Merge split-K partials: Ob = (sum_ch O) / (sum_ch l), bf16.
// ---------------------------------------------------------------------------
__global__ __launch_bounds__(256) void k_merge(const float* __restrict__ Opart,
                                               const float* __restrict__ Lpart,
                                               ushort_t* __restrict__ Ob) {
    int t = blockIdx.x * 256 + threadIdx.x;
    int e = t * 4;
    int c = e & (HD - 1);
    int row = (e >> 6) % NTOK;
    int h = e / (NTOK * HD);
    const int ostride = HEADS * NTOK * HD;
    float4 s = {0.f, 0.f, 0.f, 0.f};
    float l = 0.f;
    #pragma unroll
    for (int ch = 0; ch < CHUNKS; ch++) {
        float4 v = *(const float4*)&Opart[(size_t)ch * ostride + e];
        s.x += v.x; s.y += v.y; s.z += v.z; s.w += v.w;
        l += Lpart[(size_t)(ch * HEADS + h) * NTOK + row];
    }
    float inv = 1.0f / l;
    ushort4 o = make_ushort4(f2bf(s.x * inv), f2bf(s.y * inv),
                             f2bf(s.z * inv), f2bf(s.w * inv));
    *(ushort4*)&Ob[(size_t)row * DIM + h * HD + c] = o;
}

// ---------------------------------------------------------------------------
// Output projection: 128(M)x64(N) tiles -> 216 blocks, BK=32,
// global_load_lds DMA staging, 12 KB LDS. 2x2 waves: wave = 64 rows x 32 cols.
// ---------------------------------------------------------------------------
__global__ __launch_bounds__(256) void k_gemm_proj(
    const ushort_t* __restrict__ Ob, const ushort_t* __restrict__ WTp,
    const float* __restrict__ bp, float* __restrict__ out) {
    __shared__ __align__(16) ushort_t As[128 * 32];   // 8 KB
    __shared__ __align__(16) ushort_t Bs[64 * 32];    // 4 KB
    int tid = threadIdx.x;
    int wave = tid >> 6, lane = tid & 63, quad = lane >> 4, l16 = lane & 15;
    int wx = wave & 1, wy = wave >> 1;
    int nb = blockIdx.x * 64, mb = blockIdx.y * 128;

    f32x4 zero = {0.f, 0.f, 0.f, 0.f};
    f32x4 acc[4][2];
    #pragma unroll
    for (int i = 0; i < 4; i++)
        #pragma unroll
        for (int j = 0; j < 2; j++) acc[i][j] = zero;

    int rl = lane >> 2;
    int cl = (lane & 3) * 8;
    const ushort_t* gA = Ob + (size_t)(mb + wave * 32 + rl) * DIM + cl;
    const ushort_t* gB = WTp + (size_t)(nb + wave * 16 + rl) * DIM + cl;
    ushort_t* lA = &As[(wave * 32) * 32];
    ushort_t* lB = &Bs[(wave * 16) * 32];

    for (int k0 = 0; k0 < DIM; k0 += 32) {
        __syncthreads();
        gload_lds16(gA + k0,            lA);
        gload_lds16(gA + k0 + 16 * DIM, lA + 16 * 32);
        gload_lds16(gB + k0,            lB);
        __syncthreads();
        bf16x8 af[4], bf[2];
        #pragma unroll
        for (int i = 0; i < 4; i++)
            af[i] = *(const bf16x8*)&As[(wy * 64 + i * 16 + l16) * 32 + quad * 8];
        #pragma unroll
        for (int j = 0; j < 2; j++)
            bf[j] = *(const bf16x8*)&Bs[(wx * 32 + j * 16 + l16) * 32 + quad * 8];
        #pragma unroll
        for (int i = 0; i < 4; i++)
            #pragma unroll
            for (int j = 0; j < 2; j++)
                acc[i][j] = __builtin_amdgcn_mfma_f32_16x16x32_bf16(af[i], bf[j], acc[i][j], 0, 0, 0);
    }

    #pragma unroll
    for (int j = 0; j < 2; j++) {
        int col = nb + wx * 32 + j * 16 + l16;
        float bval = bp[col];
        #pragma unroll
        for (int i = 0; i < 4; i++) {
            #pragma unroll
            for (int r = 0; r < 4; r++) {
                int row = mb + wy * 64 + i * 16 + quad * 4 + r;
                out[(size_t)row * DIM + col] = acc[i][j][r] + bval;
            }
        }
    }
}

// ---------------------------------------------------------------------------
extern "C" void kernel_launch(void* const* d_in, const int* in_sizes, int n_in,
                              void* d_out, int out_size, void* d_ws, size_t ws_size,
                              hipStream_t stream) {
    const float* x   = (const float*)d_in[0];
    const float* Wq  = (const float*)d_in[1];
    const float* bq  = (const float*)d_in[2];
    const float* Wk  = (const float*)d_in[3];
    const float* bk  = (const float*)d_in[4];
    const float* Wv  = (const float*)d_in[5];
    const float* bv  = (const float*)d_in[6];
    const float* Wp  = (const float*)d_in[7];
    const float* bp  = (const float*)d_in[8];
    const float* rph = (const float*)d_in[9];
    const float* rpw = (const float*)d_in[10];
    const float* Aq  = (const float*)d_in[11];
    const float* Bq  = (const float*)d_in[12];
    const float* Ak  = (const float*)d_in[13];
    const float* Bk  = (const float*)d_in[14];
    const float* Av  = (const float*)d_in[15];
    const float* Bv  = (const float*)d_in[16];
    float* out = (float*)d_out;

    char* w = (char*)d_ws;
    size_t off = 0;
    auto carve = [&](size_t bytes) {
        char* p = w + off;
        off += (bytes + 255) & ~(size_t)255;
        return p;
    };
    ushort_t* xb    = (ushort_t*)carve((size_t)NTOK * DIM * 2);
    ushort_t* WT    = (ushort_t*)carve((size_t)4 * DIM * DIM * 2);
    ushort_t* Qb    = (ushort_t*)carve((size_t)HEADS * NTOK * HD * 2);
    ushort_t* Kb    = (ushort_t*)carve((size_t)HEADS * NTOK * HD * 2);
    ushort_t* Vtb   = (ushort_t*)carve((size_t)HEADS * HD * NTOK * 2);
    float*    relH  = (float*)carve((size_t)HEADS * NTOK * GRD * 4);
    ushort_t* relWb = (ushort_t*)carve((size_t)HEADS * NTOK * GRD * 2);
    ushort_t* Ob    = (ushort_t*)carve((size_t)NTOK * DIM * 2);
    float*    Opart = (float*)carve((size_t)CHUNKS * HEADS * NTOK * HD * 4);
    float*    Lpart = (float*)carve((size_t)CHUNKS * HEADS * NTOK * 4);
    ushort_t* rphb  = (ushort_t*)carve((size_t)(2 * GRD - 1) * HD * 2);
    ushort_t* rpwb  = (ushort_t*)carve((size_t)(2 * GRD - 1) * HD * 2);

    k_prep<<<dim3(2304), dim3(256), 0, stream>>>(
        x, xb, rph, rpw, rphb, rpwb,
        Wq, Wk, Wv, Wp, Aq, Bq, Ak, Bk, Av, Bv, WT);
    k_gemm_qkv<<<dim3(36, 18), dim3(256), 0, stream>>>(
        xb, WT, bq, bk, bv, Qb, Kb, Vtb);
    k_relmm<<<dim3(288), dim3(256), 0, stream>>>(
        Qb, rphb, rpwb, relH, relWb);
    k_attn<<<dim3(HEADS * CHUNKS, NTOK / 128), dim3(256), 0, stream>>>(
        Qb, Kb, Vtb, relH, relWb, Opart, Lpart);
    k_merge<<<dim3(HEADS * NTOK * HD / (256 * 4)), dim3(256), 0, stream>>>(
        Opart, Lpart, Ob);
    k_gemm_proj<<<dim3(12, 18), dim3(256), 0, stream>>>(
        Ob, WT + (size_t)3 * DIM * DIM, bp, out);
}

// Round 4
// 193.407 us; speedup vs baseline: 1.1128x; 1.0161x over previous
//
#include <hip/hip_runtime.h>

// ---------------------------------------------------------------------------
// LoRA_Attention: fold LoRA into weights; bf16 MFMA GEMMs; split-K flash
// attention. R12: k_attn __launch_bounds__(256,3). Evidence (R10/R11):
// VGPR_Count is ARCH-only; AGPR block adds ~64 (R10's (256,4)=128-budget
// split 64+64 and spilled; R11 plain = 108+64 ≈ 172 total -> 2 waves/SIMD,
// occupancy 15%). (256,3) sets budget 170 — a ~4-reg trim, keeps ~104 arch
// + 64 AGPR spill-free, capacity 2 -> 3 blocks/CU (LDS 38400 allows 4).
// relW direct-global bf16; rhs in LDS; exp2 softmax no-max; XCD-local grid.
// ---------------------------------------------------------------------------

#define DIM   768
#define HEADS 12
#define HD    64
#define NTOK  2304
#define RANK  8
#define GRD   48
#define CHUNKS 4
#define LOG2E 1.44269504088896f

typedef __attribute__((ext_vector_type(8))) short bf16x8;
typedef __attribute__((ext_vector_type(4))) float f32x4;
typedef unsigned short ushort_t;

__device__ __forceinline__ unsigned short f2bf(float x) {
    union { float f; unsigned u; } v; v.f = x;
    unsigned r = v.u + 0x7fffu + ((v.u >> 16) & 1u);
    return (unsigned short)(r >> 16);
}
__device__ __forceinline__ float bf2f(unsigned short h) {
    return __uint_as_float(((unsigned)h) << 16);
}
__device__ __forceinline__ void gload_lds16(const ushort_t* g, ushort_t* l) {
    __builtin_amdgcn_global_load_lds(
        (const __attribute__((address_space(1))) unsigned int*)g,
        (__attribute__((address_space(3))) unsigned int*)l, 16, 0, 0);
}

// ---------------------------------------------------------------------------
// k_prep: fold LoRA into transposed weights (all 2304 blocks) + convert
// x / rel tables to bf16 (blocks < 1740). Independent tasks, one launch.
// ---------------------------------------------------------------------------
__global__ __launch_bounds__(256) void k_prep(
    const float* __restrict__ x, ushort_t* __restrict__ xb,
    const float* __restrict__ rph, const float* __restrict__ rpw,
    ushort_t* __restrict__ rphb, ushort_t* __restrict__ rpwb,
    const float* __restrict__ Wq, const float* __restrict__ Wk,
    const float* __restrict__ Wv, const float* __restrict__ Wp,
    const float* __restrict__ Aq, const float* __restrict__ Bq,
    const float* __restrict__ Ak, const float* __restrict__ Bk,
    const float* __restrict__ Av, const float* __restrict__ Bv,
    ushort_t* __restrict__ WT) {
    int bid = blockIdx.x, tid = threadIdx.x;

    if (bid < 1740) {
        if (bid < 1728) {
            int idx = (bid * 256 + tid) * 4;
            float4 v = *(const float4*)(x + idx);
            ushort4 o = make_ushort4(f2bf(v.x), f2bf(v.y), f2bf(v.z), f2bf(v.w));
            *(ushort4*)(xb + idx) = o;
        } else {
            int e = ((bid - 1728) * 256 + tid) * 4;
            const int TSZ = (2 * GRD - 1) * HD;   // 6080
            if (e < TSZ) {
                float4 v = *(const float4*)(rph + e);
                ushort4 o = make_ushort4(f2bf(v.x), f2bf(v.y), f2bf(v.z), f2bf(v.w));
                *(ushort4*)(rphb + e) = o;
            } else if (e < 2 * TSZ) {
                float4 v = *(const float4*)(rpw + e - TSZ);
                ushort4 o = make_ushort4(f2bf(v.x), f2bf(v.y), f2bf(v.z), f2bf(v.w));
                *(ushort4*)(rpwb + e - TSZ) = o;
            }
        }
    }

    int kb = (bid % 24) * 32;
    int nb = (bid / 24) * 32;
    int sel = nb / DIM, nmod = nb % DIM;
    const float* W = (sel == 0) ? Wq : (sel == 1) ? Wk : (sel == 2) ? Wv : Wp;
    const float* A = (sel == 0) ? Aq : (sel == 1) ? Ak : Av;
    const float* B = (sel == 0) ? Bq : (sel == 1) ? Bk : Bv;
    __shared__ float T[32][33];
    for (int i = tid; i < 1024; i += 256) {
        int kl = i >> 5, nl = i & 31;
        float v = W[(kb + kl) * DIM + nmod + nl];
        if (sel < 3) {
            #pragma unroll
            for (int r = 0; r < RANK; r++)
                v += A[(kb + kl) * RANK + r] * B[r * DIM + nmod + nl];
        }
        T[kl][nl] = v;
    }
    __syncthreads();
    for (int i = tid; i < 1024; i += 256) {
        int nl = i >> 5, kl = i & 31;
        WT[(size_t)(nb + nl) * DIM + kb + kl] = f2bf(T[kl][nl]);
    }
}

// ---------------------------------------------------------------------------
// QKV GEMM: 128(M)x64(N) tiles -> 648 blocks (~2.5/CU, no packing tail),
// BK=32, global_load_lds DMA, 12 KB LDS. Waves 2x2: wave = 64 rows x 32 cols.
// ---------------------------------------------------------------------------
__global__ __launch_bounds__(256) void k_gemm_qkv(
    const ushort_t* __restrict__ xb, const ushort_t* __restrict__ WT,
    const float* __restrict__ bq, const float* __restrict__ bk,
    const float* __restrict__ bv,
    ushort_t* __restrict__ Qb, ushort_t* __restrict__ Kb,
    ushort_t* __restrict__ Vtb) {
    __shared__ __align__(16) ushort_t As[128 * 32];   // 8 KB
    __shared__ __align__(16) ushort_t Bs[64 * 32];    // 4 KB
    int tid = threadIdx.x;
    int wave = tid >> 6, lane = tid & 63, quad = lane >> 4, l16 = lane & 15;
    int wx = wave & 1, wy = wave >> 1;
    int nb = blockIdx.x * 64, mb = blockIdx.y * 128;

    f32x4 zero = {0.f, 0.f, 0.f, 0.f};
    f32x4 acc[4][2];
    #pragma unroll
    for (int i = 0; i < 4; i++)
        #pragma unroll
        for (int j = 0; j < 2; j++) acc[i][j] = zero;

    int rl = lane >> 2;            // 0..15
    int cl = (lane & 3) * 8;       // element col within 32
    const ushort_t* gA = xb + (size_t)(mb + wave * 32 + rl) * DIM + cl;
    const ushort_t* gB = WT + (size_t)(nb + wave * 16 + rl) * DIM + cl;
    ushort_t* lA = &As[(wave * 32) * 32];
    ushort_t* lB = &Bs[(wave * 16) * 32];

    for (int k0 = 0; k0 < DIM; k0 += 32) {
        __syncthreads();
        gload_lds16(gA + k0,            lA);
        gload_lds16(gA + k0 + 16 * DIM, lA + 16 * 32);
        gload_lds16(gB + k0,            lB);
        __syncthreads();
        bf16x8 af[4], bf[2];
        #pragma unroll
        for (int i = 0; i < 4; i++)
            af[i] = *(const bf16x8*)&As[(wy * 64 + i * 16 + l16) * 32 + quad * 8];
        #pragma unroll
        for (int j = 0; j < 2; j++)
            bf[j] = *(const bf16x8*)&Bs[(wx * 32 + j * 16 + l16) * 32 + quad * 8];
        #pragma unroll
        for (int i = 0; i < 4; i++)
            #pragma unroll
            for (int j = 0; j < 2; j++)
                acc[i][j] = __builtin_amdgcn_mfma_f32_16x16x32_bf16(af[i], bf[j], acc[i][j], 0, 0, 0);
    }

    #pragma unroll
    for (int j = 0; j < 2; j++) {
        int col = nb + wx * 32 + j * 16 + l16;
        int sel = col / DIM, rem = col % DIM;
        int hh = rem >> 6, cc = rem & 63;
        const float* bias = (sel == 0) ? bq : (sel == 1) ? bk : bv;
        float bval = bias[rem];
        #pragma unroll
        for (int i = 0; i < 4; i++) {
            #pragma unroll
            for (int r = 0; r < 4; r++) {
                int row = mb + wy * 64 + i * 16 + quad * 4 + r;
                unsigned short o = f2bf(acc[i][j][r] + bval);
                if (sel == 0)      Qb[(size_t)(hh * NTOK + row) * HD + cc] = o;
                else if (sel == 1) Kb[(size_t)(hh * NTOK + row) * HD + cc] = o;
                else               Vtb[(size_t)(hh * HD + cc) * NTOK + row] = o;
            }
        }
    }
}

// ---------------------------------------------------------------------------
// Rel-pos bias via MFMA (outputs pre-scaled by log2 e).
// relW emitted as bf16 (k_attn reads it directly from global); relH
// stays f32 (staged+converted into k_attn's small rhs LDS buffer).
// ---------------------------------------------------------------------------
__global__ __launch_bounds__(256) void k_relmm(
    const ushort_t* __restrict__ Qb, const ushort_t* __restrict__ rphb,
    const ushort_t* __restrict__ rpwb, float* __restrict__ relH,
    ushort_t* __restrict__ relWb) {
    int id = blockIdx.x * 4 + (threadIdx.x >> 6);
    int lane = threadIdx.x & 63, quad = lane >> 4, l16 = lane & 15;
    bool isW = id >= 576;
    int t = isW ? id - 576 : id;
    int h = t / GRD, g = t % GRD;
    const ushort_t* tab = isW ? rpwb : rphb;

    f32x4 zero = {0.f, 0.f, 0.f, 0.f};
    f32x4 acc[3][3];
    #pragma unroll
    for (int i = 0; i < 3; i++)
        #pragma unroll
        for (int j = 0; j < 3; j++) acc[i][j] = zero;

    bf16x8 bfr[3][2];
    #pragma unroll
    for (int ct = 0; ct < 3; ct++) {
        int trow = g + 47 - (ct * 16 + l16);
        bfr[ct][0] = *(const bf16x8*)&tab[(size_t)trow * HD + quad * 8];
        bfr[ct][1] = *(const bf16x8*)&tab[(size_t)trow * HD + 32 + quad * 8];
    }
    #pragma unroll
    for (int ms = 0; ms < 3; ms++) {
        int m = ms * 16 + l16;
        int n = isW ? m * GRD + g : g * GRD + m;
        bf16x8 a0 = *(const bf16x8*)&Qb[(size_t)(h * NTOK + n) * HD + quad * 8];
        bf16x8 a1 = *(const bf16x8*)&Qb[(size_t)(h * NTOK + n) * HD + 32 + quad * 8];
        #pragma unroll
        for (int ct = 0; ct < 3; ct++) {
            acc[ms][ct] = __builtin_amdgcn_mfma_f32_16x16x32_bf16(a0, bfr[ct][0], acc[ms][ct], 0, 0, 0);
            acc[ms][ct] = __builtin_amdgcn_mfma_f32_16x16x32_bf16(a1, bfr[ct][1], acc[ms][ct], 0, 0, 0);
        }
    }
    #pragma unroll
    for (int ms = 0; ms < 3; ms++) {
        #pragma unroll
        for (int ct = 0; ct < 3; ct++) {
            #pragma unroll
            for (int r = 0; r < 4; r++) {
                int m = ms * 16 + quad * 4 + r;
                int n = isW ? m * GRD + g : g * GRD + m;
                int col = ct * 16 + l16;
                float val = acc[ms][ct][r] * LOG2E;
                if (isW)
                    relWb[(size_t)(h * NTOK + n) * GRD + col] = f2bf(val);
                else
                    relH[(size_t)(h * NTOK + n) * GRD + col] = val;
            }
        }
    }
}

// ---------------------------------------------------------------------------
// Flash attention, split-K. Block = (128 q-rows, head, chunk of 576 keys).
// Grid x = h*4+chunk (XCD-local K/V sharing). Coalesced uint4 reg-prefetch
// -> stride-68 LDS; S^T compute. relW read directly from global as bf16
// uint2 pairs (prefetched per kt-iteration) -> LDS 38400 B. rhs in LDS.
// __launch_bounds__(256,3): total reg budget 170 (arch+AGPR) -> 3 waves/EU
// -> 3 blocks/CU (plain bounds landed 108 arch + ~64 AGPR = 2 waves/EU).
// ---------------------------------------------------------------------------
__global__ __launch_bounds__(256, 3) void k_attn(
    const ushort_t* __restrict__ Qb, const ushort_t* __restrict__ Kb,
    const ushort_t* __restrict__ Vtb, const float* __restrict__ relH,
    const ushort_t* __restrict__ relWb, float* __restrict__ Opart,
    float* __restrict__ Lpart) {
    int h = blockIdx.x >> 2, chunk = blockIdx.x & 3, qt = blockIdx.y;
    int tid = threadIdx.x;
    int wave = tid >> 6, lane = tid & 63, quad = lane >> 4, l16 = lane & 15;
    int qbase = qt * 128;
    int kbase = chunk * 576;

    __shared__ __align__(16) ushort_t Ks[64 * 68];
    __shared__ __align__(16) ushort_t Vs[64 * 68];
    __shared__ __align__(16) ushort_t Ps[4][32 * 68];
    __shared__ __align__(16) ushort_t rhs[128 * 14];

    for (int i = tid; i < 128 * 12; i += 256) {
        int r = i / 12, c = i % 12;
        rhs[r * 14 + c] = f2bf(relH[(size_t)(h * NTOK + qbase + r) * GRD + chunk * 12 + c]);
    }

    bf16x8 qf[2][2];
    #pragma unroll
    for (int s = 0; s < 2; s++) {
        int qrow = qbase + wave * 32 + s * 16 + l16;
        qf[s][0] = *(const bf16x8*)&Qb[(size_t)(h * NTOK + qrow) * HD + quad * 8];
        qf[s][1] = *(const bf16x8*)&Qb[(size_t)(h * NTOK + qrow) * HD + 32 + quad * 8];
    }

    int r0 = tid >> 3, c0 = (tid & 7) * 8;
    const ushort_t* kg0 = Kb + (size_t)(h * NTOK + r0) * HD + c0;
    const ushort_t* kg1 = Kb + (size_t)(h * NTOK + r0 + 32) * HD + c0;
    const ushort_t* vg0 = Vtb + (size_t)(h * HD + r0) * NTOK + c0;
    const ushort_t* vg1 = Vtb + (size_t)(h * HD + r0 + 32) * NTOK + c0;
    int sk0 = r0 * 68 + c0, sk1 = sk0 + 32 * 68;

    // per-lane relW row pointers (rows owned by this lane across s=0,1)
    const ushort_t* rw0 = relWb + (size_t)(h * NTOK + qbase + wave * 32 + l16) * GRD;
    const ushort_t* rw1 = rw0 + (size_t)16 * GRD;

    float lacc[2] = {0.f, 0.f};
    f32x4 zero = {0.f, 0.f, 0.f, 0.f};
    f32x4 oacc[2][4];
    #pragma unroll
    for (int s = 0; s < 2; s++)
        #pragma unroll
        for (int cs = 0; cs < 4; cs++) oacc[s][cs] = zero;

    const float scale2 = 0.125f * LOG2E;

    uint4 rk0 = *(const uint4*)(kg0 + (size_t)kbase * HD);
    uint4 rk1 = *(const uint4*)(kg1 + (size_t)kbase * HD);
    uint4 rv0 = *(const uint4*)(vg0 + kbase);
    uint4 rv1 = *(const uint4*)(vg1 + kbase);

    for (int kt = 0; kt < 9; kt++) {
        int kb = kbase + kt * 64;

        // prefetch this iteration's relW bias (8B per (s,ks)); issued before
        // the barrier pair so the L2 latency hides under K/V staging + S-MFMA
        uint2 rwv[2][4];
        #pragma unroll
        for (int ks = 0; ks < 4; ks++) {
            int kb4 = kb + ks * 16 + quad * 4;
            int kh = kb4 / 48;
            int kw0 = kb4 - kh * 48;
            rwv[0][ks] = *(const uint2*)(rw0 + kw0);
            rwv[1][ks] = *(const uint2*)(rw1 + kw0);
        }

        __syncthreads();
        *(uint4*)&Ks[sk0] = rk0;  *(uint4*)&Ks[sk1] = rk1;
        *(uint4*)&Vs[sk0] = rv0;  *(uint4*)&Vs[sk1] = rv1;
        __syncthreads();
        if (kt < 8) {
            int kbn = kb + 64;
            rk0 = *(const uint4*)(kg0 + (size_t)kbn * HD);
            rk1 = *(const uint4*)(kg1 + (size_t)kbn * HD);
            rv0 = *(const uint4*)(vg0 + kbn);
            rv1 = *(const uint4*)(vg1 + kbn);
        }

        #pragma unroll
        for (int ks = 0; ks < 4; ks++) {
            bf16x8 kf0 = *(const bf16x8*)&Ks[(ks * 16 + l16) * 68 + quad * 8];
            bf16x8 kf1 = *(const bf16x8*)&Ks[(ks * 16 + l16) * 68 + 32 + quad * 8];
            f32x4 st[2];
            #pragma unroll
            for (int s = 0; s < 2; s++) {
                f32x4 z = zero;
                z = __builtin_amdgcn_mfma_f32_16x16x32_bf16(kf0, qf[s][0], z, 0, 0, 0);
                z = __builtin_amdgcn_mfma_f32_16x16x32_bf16(kf1, qf[s][1], z, 0, 0, 0);
                st[s] = z;
            }
            int kb4 = kb + ks * 16 + quad * 4;
            int khl = kb4 / 48 - chunk * 12;
            #pragma unroll
            for (int s = 0; s < 2; s++) {
                int row = wave * 32 + s * 16 + l16;
                float rh = bf2f(rhs[row * 14 + khl]);
                uint2 u = rwv[s][ks];
                float p0 = __builtin_amdgcn_exp2f(st[s][0] * scale2 + rh + __uint_as_float(u.x << 16));
                float p1 = __builtin_amdgcn_exp2f(st[s][1] * scale2 + rh + __uint_as_float(u.x & 0xffff0000u));
                float p2 = __builtin_amdgcn_exp2f(st[s][2] * scale2 + rh + __uint_as_float(u.y << 16));
                float p3 = __builtin_amdgcn_exp2f(st[s][3] * scale2 + rh + __uint_as_float(u.y & 0xffff0000u));
                lacc[s] += (p0 + p1) + (p2 + p3);
                uint2 w;
                w.x = __builtin_amdgcn_perm(__float_as_uint(p1), __float_as_uint(p0), 0x07060302u);
                w.y = __builtin_amdgcn_perm(__float_as_uint(p3), __float_as_uint(p2), 0x07060302u);
                *(uint2*)&Ps[wave][(s * 16 + l16) * 68 + ks * 16 + quad * 4] = w;
            }
        }

        bf16x8 vf[4][2];
        #pragma unroll
        for (int cs = 0; cs < 4; cs++) {
            vf[cs][0] = *(const bf16x8*)&Vs[(cs * 16 + l16) * 68 + quad * 8];
            vf[cs][1] = *(const bf16x8*)&Vs[(cs * 16 + l16) * 68 + 32 + quad * 8];
        }
        #pragma unroll
        for (int s = 0; s < 2; s++) {
            bf16x8 pa0 = *(const bf16x8*)&Ps[wave][(s * 16 + l16) * 68 + quad * 8];
            bf16x8 pa1 = *(const bf16x8*)&Ps[wave][(s * 16 + l16) * 68 + 32 + quad * 8];
            #pragma unroll
            for (int cs = 0; cs < 4; cs++) {
                oacc[s][cs] = __builtin_amdgcn_mfma_f32_16x16x32_bf16(pa0, vf[cs][0], oacc[s][cs], 0, 0, 0);
                oacc[s][cs] = __builtin_amdgcn_mfma_f32_16x16x32_bf16(pa1, vf[cs][1], oacc[s][cs], 0, 0, 0);
            }
        }
    }

    #pragma unroll
    for (int s = 0; s < 2; s++) {
        float l = lacc[s];
        l += __shfl_xor(l, 16);
        l += __shfl_xor(l, 32);
        lacc[s] = l;
    }

    size_t obase = (size_t)(chunk * HEADS + h) * NTOK;
    #pragma unroll
    for (int s = 0; s < 2; s++) {
        #pragma unroll
        for (int cs = 0; cs < 4; cs++) {
            #pragma unroll
            for (int r = 0; r < 4; r++) {
                int row = qbase + wave * 32 + s * 16 + quad * 4 + r;
                Opart[(obase + row) * HD + cs * 16 + l16] = oacc[s][cs][r];
            }
        }
        if (quad == 0)
            Lpart[obase + qbase + wave * 32 + s * 16 + l16] = lacc[s];
    }
}

// ---------------------------------------------------------------------------
// Merge split-K partials: Ob = (sum_ch O) / (sum_ch l), bf16.
// ---------------------------------------------------------------------------
__global__ __launch_bounds__(256) void k_merge(const float* __restrict__ Opart,
                                               const float* __restrict__ Lpart,
                                               ushort_t* __restrict__ Ob) {
    int t = blockIdx.x * 256 + threadIdx.x;
    int e = t * 4;
    int c = e & (HD - 1);
    int row = (e >> 6) % NTOK;
    int h = e / (NTOK * HD);
    const int ostride = HEADS * NTOK * HD;
    float4 s = {0.f, 0.f, 0.f, 0.f};
    float l = 0.f;
    #pragma unroll
    for (int ch = 0; ch < CHUNKS; ch++) {
        float4 v = *(const float4*)&Opart[(size_t)ch * ostride + e];
        s.x += v.x; s.y += v.y; s.z += v.z; s.w += v.w;
        l += Lpart[(size_t)(ch * HEADS + h) * NTOK + row];
    }
    float inv = 1.0f / l;
    ushort4 o = make_ushort4(f2bf(s.x * inv), f2bf(s.y * inv),
                             f2bf(s.z * inv), f2bf(s.w * inv));
    *(ushort4*)&Ob[(size_t)row * DIM + h * HD + c] = o;
}

// ---------------------------------------------------------------------------
// Output projection: 128(M)x64(N) tiles -> 216 blocks, BK=32,
// global_load_lds DMA staging, 12 KB LDS. 2x2 waves: wave = 64 rows x 32 cols.
// ---------------------------------------------------------------------------
__global__ __launch_bounds__(256) void k_gemm_proj(
    const ushort_t* __restrict__ Ob, const ushort_t* __restrict__ WTp,
    const float* __restrict__ bp, float* __restrict__ out) {
    __shared__ __align__(16) ushort_t As[128 * 32];   // 8 KB
    __shared__ __align__(16) ushort_t Bs[64 * 32];    // 4 KB
    int tid = threadIdx.x;
    int wave = tid >> 6, lane = tid & 63, quad = lane >> 4, l16 = lane & 15;
    int wx = wave & 1, wy = wave >> 1;
    int nb = blockIdx.x * 64, mb = blockIdx.y * 128;

    f32x4 zero = {0.f, 0.f, 0.f, 0.f};
    f32x4 acc[4][2];
    #pragma unroll
    for (int i = 0; i < 4; i++)
        #pragma unroll
        for (int j = 0; j < 2; j++) acc[i][j] = zero;

    int rl = lane >> 2;
    int cl = (lane & 3) * 8;
    const ushort_t* gA = Ob + (size_t)(mb + wave * 32 + rl) * DIM + cl;
    const ushort_t* gB = WTp + (size_t)(nb + wave * 16 + rl) * DIM + cl;
    ushort_t* lA = &As[(wave * 32) * 32];
    ushort_t* lB = &Bs[(wave * 16) * 32];

    for (int k0 = 0; k0 < DIM; k0 += 32) {
        __syncthreads();
        gload_lds16(gA + k0,            lA);
        gload_lds16(gA + k0 + 16 * DIM, lA + 16 * 32);
        gload_lds16(gB + k0,            lB);
        __syncthreads();
        bf16x8 af[4], bf[2];
        #pragma unroll
        for (int i = 0; i < 4; i++)
            af[i] = *(const bf16x8*)&As[(wy * 64 + i * 16 + l16) * 32 + quad * 8];
        #pragma unroll
        for (int j = 0; j < 2; j++)
            bf[j] = *(const bf16x8*)&Bs[(wx * 32 + j * 16 + l16) * 32 + quad * 8];
        #pragma unroll
        for (int i = 0; i < 4; i++)
            #pragma unroll
            for (int j = 0; j < 2; j++)
                acc[i][j] = __builtin_amdgcn_mfma_f32_16x16x32_bf16(af[i], bf[j], acc[i][j], 0, 0, 0);
    }

    #pragma unroll
    for (int j = 0; j < 2; j++) {
        int col = nb + wx * 32 + j * 16 + l16;
        float bval = bp[col];
        #pragma unroll
        for (int i = 0; i < 4; i++) {
            #pragma unroll
            for (int r = 0; r < 4; r++) {
                int row = mb + wy * 64 + i * 16 + quad * 4 + r;
                out[(size_t)row * DIM + col] = acc[i][j][r] + bval;
            }
        }
    }
}

// ---------------------------------------------------------------------------
extern "C" void kernel_launch(void* const* d_in, const int* in_sizes, int n_in,
                              void* d_out, int out_size, void* d_ws, size_t ws_size,
                              hipStream_t stream) {
    const float* x   = (const float*)d_in[0];
    const float* Wq  = (const float*)d_in[1];
    const float* bq  = (const float*)d_in[2];
    const float* Wk  = (const float*)d_in[3];
    const float* bk  = (const float*)d_in[4];
    const float* Wv  = (const float*)d_in[5];
    const float* bv  = (const float*)d_in[6];
    const float* Wp  = (const float*)d_in[7];
    const float* bp  = (const float*)d_in[8];
    const float* rph = (const float*)d_in[9];
    const float* rpw = (const float*)d_in[10];
    const float* Aq  = (const float*)d_in[11];
    const float* Bq  = (const float*)d_in[12];
    const float* Ak  = (const float*)d_in[13];
    const float* Bk  = (const float*)d_in[14];
    const float* Av  = (const float*)d_in[15];
    const float* Bv  = (const float*)d_in[16];
    float* out = (float*)d_out;

    char* w = (char*)d_ws;
    size_t off = 0;
    auto carve = [&](size_t bytes) {
        char* p = w + off;
        off += (bytes + 255) & ~(size_t)255;
        return p;
    };
    ushort_t* xb    = (ushort_t*)carve((size_t)NTOK * DIM * 2);
    ushort_t* WT    = (ushort_t*)carve((size_t)4 * DIM * DIM * 2);
    ushort_t* Qb    = (ushort_t*)carve((size_t)HEADS * NTOK * HD * 2);
    ushort_t* Kb    = (ushort_t*)carve((size_t)HEADS * NTOK * HD * 2);
    ushort_t* Vtb   = (ushort_t*)carve((size_t)HEADS * HD * NTOK * 2);
    float*    relH  = (float*)carve((size_t)HEADS * NTOK * GRD * 4);
    ushort_t* relWb = (ushort_t*)carve((size_t)HEADS * NTOK * GRD * 2);
    ushort_t* Ob    = (ushort_t*)carve((size_t)NTOK * DIM * 2);
    float*    Opart = (float*)carve((size_t)CHUNKS * HEADS * NTOK * HD * 4);
    float*    Lpart = (float*)carve((size_t)CHUNKS * HEADS * NTOK * 4);
    ushort_t* rphb  = (ushort_t*)carve((size_t)(2 * GRD - 1) * HD * 2);
    ushort_t* rpwb  = (ushort_t*)carve((size_t)(2 * GRD - 1) * HD * 2);

    k_prep<<<dim3(2304), dim3(256), 0, stream>>>(
        x, xb, rph, rpw, rphb, rpwb,
        Wq, Wk, Wv, Wp, Aq, Bq, Ak, Bk, Av, Bv, WT);
    k_gemm_qkv<<<dim3(36, 18), dim3(256), 0, stream>>>(
        xb, WT, bq, bk, bv, Qb, Kb, Vtb);
    k_relmm<<<dim3(288), dim3(256), 0, stream>>>(
        Qb, rphb, rpwb, relH, relWb);
    k_attn<<<dim3(HEADS * CHUNKS, NTOK / 128), dim3(256), 0, stream>>>(
        Qb, Kb, Vtb, relH, relWb, Opart, Lpart);
    k_merge<<<dim3(HEADS * NTOK * HD / (256 * 4)), dim3(256), 0, stream>>>(
        Opart, Lpart, Ob);
    k_gemm_proj<<<dim3(12, 18), dim3(256), 0, stream>>>(
        Ob, WT + (size_t)3 * DIM * DIM, bp, out);
}

// Round 5
// 192.810 us; speedup vs baseline: 1.1162x; 1.0031x over previous
//
#include <hip/hip_runtime.h>

// ---------------------------------------------------------------------------
// LoRA_Attention: fold LoRA into weights; bf16 MFMA GEMMs; split-K flash
// attention. R13: CHUNKS 4 -> 3 (768 keys/chunk, 12 kt). Grid 648 <= 768
// capacity (3 blk/CU at (256,3), R12-proven no-spill) -> single-phase, kills
// the 96-block tail that cost ~25% of k_attn (R12: occupancy 19.7% not 24%
// = half-empty tail phase in the average). Opart/Lpart -25%. rhs slice now
// 16 cols (pow2 indexing), stride 18 (gcd(9,32)=1, conflict-free).
// relW direct-global bf16; exp2 softmax no-max; XCD-local grid.
// ---------------------------------------------------------------------------

#define DIM   768
#define HEADS 12
#define HD    64
#define NTOK  2304
#define RANK  8
#define GRD   48
#define CHUNKS 3
#define KEYS_PER_CHUNK 768
#define KT_PER 12
#define LOG2E 1.44269504088896f

typedef __attribute__((ext_vector_type(8))) short bf16x8;
typedef __attribute__((ext_vector_type(4))) float f32x4;
typedef unsigned short ushort_t;

__device__ __forceinline__ unsigned short f2bf(float x) {
    union { float f; unsigned u; } v; v.f = x;
    unsigned r = v.u + 0x7fffu + ((v.u >> 16) & 1u);
    return (unsigned short)(r >> 16);
}
__device__ __forceinline__ float bf2f(unsigned short h) {
    return __uint_as_float(((unsigned)h) << 16);
}
__device__ __forceinline__ void gload_lds16(const ushort_t* g, ushort_t* l) {
    __builtin_amdgcn_global_load_lds(
        (const __attribute__((address_space(1))) unsigned int*)g,
        (__attribute__((address_space(3))) unsigned int*)l, 16, 0, 0);
}

// ---------------------------------------------------------------------------
// k_prep: fold LoRA into transposed weights (all 2304 blocks) + convert
// x / rel tables to bf16 (blocks < 1740). Independent tasks, one launch.
// ---------------------------------------------------------------------------
__global__ __launch_bounds__(256) void k_prep(
    const float* __restrict__ x, ushort_t* __restrict__ xb,
    const float* __restrict__ rph, const float* __restrict__ rpw,
    ushort_t* __restrict__ rphb, ushort_t* __restrict__ rpwb,
    const float* __restrict__ Wq, const float* __restrict__ Wk,
    const float* __restrict__ Wv, const float* __restrict__ Wp,
    const float* __restrict__ Aq, const float* __restrict__ Bq,
    const float* __restrict__ Ak, const float* __restrict__ Bk,
    const float* __restrict__ Av, const float* __restrict__ Bv,
    ushort_t* __restrict__ WT) {
    int bid = blockIdx.x, tid = threadIdx.x;

    if (bid < 1740) {
        if (bid < 1728) {
            int idx = (bid * 256 + tid) * 4;
            float4 v = *(const float4*)(x + idx);
            ushort4 o = make_ushort4(f2bf(v.x), f2bf(v.y), f2bf(v.z), f2bf(v.w));
            *(ushort4*)(xb + idx) = o;
        } else {
            int e = ((bid - 1728) * 256 + tid) * 4;
            const int TSZ = (2 * GRD - 1) * HD;   // 6080
            if (e < TSZ) {
                float4 v = *(const float4*)(rph + e);
                ushort4 o = make_ushort4(f2bf(v.x), f2bf(v.y), f2bf(v.z), f2bf(v.w));
                *(ushort4*)(rphb + e) = o;
            } else if (e < 2 * TSZ) {
                float4 v = *(const float4*)(rpw + e - TSZ);
                ushort4 o = make_ushort4(f2bf(v.x), f2bf(v.y), f2bf(v.z), f2bf(v.w));
                *(ushort4*)(rpwb + e - TSZ) = o;
            }
        }
    }

    int kb = (bid % 24) * 32;
    int nb = (bid / 24) * 32;
    int sel = nb / DIM, nmod = nb % DIM;
    const float* W = (sel == 0) ? Wq : (sel == 1) ? Wk : (sel == 2) ? Wv : Wp;
    const float* A = (sel == 0) ? Aq : (sel == 1) ? Ak : Av;
    const float* B = (sel == 0) ? Bq : (sel == 1) ? Bk : Bv;
    __shared__ float T[32][33];
    for (int i = tid; i < 1024; i += 256) {
        int kl = i >> 5, nl = i & 31;
        float v = W[(kb + kl) * DIM + nmod + nl];
        if (sel < 3) {
            #pragma unroll
            for (int r = 0; r < RANK; r++)
                v += A[(kb + kl) * RANK + r] * B[r * DIM + nmod + nl];
        }
        T[kl][nl] = v;
    }
    __syncthreads();
    for (int i = tid; i < 1024; i += 256) {
        int nl = i >> 5, kl = i & 31;
        WT[(size_t)(nb + nl) * DIM + kb + kl] = f2bf(T[kl][nl]);
    }
}

// ---------------------------------------------------------------------------
// QKV GEMM: 128(M)x64(N) tiles -> 648 blocks (~2.5/CU, no packing tail),
// BK=32, global_load_lds DMA, 12 KB LDS. Waves 2x2: wave = 64 rows x 32 cols.
// ---------------------------------------------------------------------------
__global__ __launch_bounds__(256) void k_gemm_qkv(
    const ushort_t* __restrict__ xb, const ushort_t* __restrict__ WT,
    const float* __restrict__ bq, const float* __restrict__ bk,
    const float* __restrict__ bv,
    ushort_t* __restrict__ Qb, ushort_t* __restrict__ Kb,
    ushort_t* __restrict__ Vtb) {
    __shared__ __align__(16) ushort_t As[128 * 32];   // 8 KB
    __shared__ __align__(16) ushort_t Bs[64 * 32];    // 4 KB
    int tid = threadIdx.x;
    int wave = tid >> 6, lane = tid & 63, quad = lane >> 4, l16 = lane & 15;
    int wx = wave & 1, wy = wave >> 1;
    int nb = blockIdx.x * 64, mb = blockIdx.y * 128;

    f32x4 zero = {0.f, 0.f, 0.f, 0.f};
    f32x4 acc[4][2];
    #pragma unroll
    for (int i = 0; i < 4; i++)
        #pragma unroll
        for (int j = 0; j < 2; j++) acc[i][j] = zero;

    int rl = lane >> 2;            // 0..15
    int cl = (lane & 3) * 8;       // element col within 32
    const ushort_t* gA = xb + (size_t)(mb + wave * 32 + rl) * DIM + cl;
    const ushort_t* gB = WT + (size_t)(nb + wave * 16 + rl) * DIM + cl;
    ushort_t* lA = &As[(wave * 32) * 32];
    ushort_t* lB = &Bs[(wave * 16) * 32];

    for (int k0 = 0; k0 < DIM; k0 += 32) {
        __syncthreads();
        gload_lds16(gA + k0,            lA);
        gload_lds16(gA + k0 + 16 * DIM, lA + 16 * 32);
        gload_lds16(gB + k0,            lB);
        __syncthreads();
        bf16x8 af[4], bf[2];
        #pragma unroll
        for (int i = 0; i < 4; i++)
            af[i] = *(const bf16x8*)&As[(wy * 64 + i * 16 + l16) * 32 + quad * 8];
        #pragma unroll
        for (int j = 0; j < 2; j++)
            bf[j] = *(const bf16x8*)&Bs[(wx * 32 + j * 16 + l16) * 32 + quad * 8];
        #pragma unroll
        for (int i = 0; i < 4; i++)
            #pragma unroll
            for (int j = 0; j < 2; j++)
                acc[i][j] = __builtin_amdgcn_mfma_f32_16x16x32_bf16(af[i], bf[j], acc[i][j], 0, 0, 0);
    }

    #pragma unroll
    for (int j = 0; j < 2; j++) {
        int col = nb + wx * 32 + j * 16 + l16;
        int sel = col / DIM, rem = col % DIM;
        int hh = rem >> 6, cc = rem & 63;
        const float* bias = (sel == 0) ? bq : (sel == 1) ? bk : bv;
        float bval = bias[rem];
        #pragma unroll
        for (int i = 0; i < 4; i++) {
            #pragma unroll
            for (int r = 0; r < 4; r++) {
                int row = mb + wy * 64 + i * 16 + quad * 4 + r;
                unsigned short o = f2bf(acc[i][j][r] + bval);
                if (sel == 0)      Qb[(size_t)(hh * NTOK + row) * HD + cc] = o;
                else if (sel == 1) Kb[(size_t)(hh * NTOK + row) * HD + cc] = o;
                else               Vtb[(size_t)(hh * HD + cc) * NTOK + row] = o;
            }
        }
    }
}

// ---------------------------------------------------------------------------
// Rel-pos bias via MFMA (outputs pre-scaled by log2 e).
// relW emitted as bf16 (k_attn reads it directly from global); relH
// stays f32 (staged+converted into k_attn's small rhs LDS buffer).
// ---------------------------------------------------------------------------
__global__ __launch_bounds__(256) void k_relmm(
    const ushort_t* __restrict__ Qb, const ushort_t* __restrict__ rphb,
    const ushort_t* __restrict__ rpwb, float* __restrict__ relH,
    ushort_t* __restrict__ relWb) {
    int id = blockIdx.x * 4 + (threadIdx.x >> 6);
    int lane = threadIdx.x & 63, quad = lane >> 4, l16 = lane & 15;
    bool isW = id >= 576;
    int t = isW ? id - 576 : id;
    int h = t / GRD, g = t % GRD;
    const ushort_t* tab = isW ? rpwb : rphb;

    f32x4 zero = {0.f, 0.f, 0.f, 0.f};
    f32x4 acc[3][3];
    #pragma unroll
    for (int i = 0; i < 3; i++)
        #pragma unroll
        for (int j = 0; j < 3; j++) acc[i][j] = zero;

    bf16x8 bfr[3][2];
    #pragma unroll
    for (int ct = 0; ct < 3; ct++) {
        int trow = g + 47 - (ct * 16 + l16);
        bfr[ct][0] = *(const bf16x8*)&tab[(size_t)trow * HD + quad * 8];
        bfr[ct][1] = *(const bf16x8*)&tab[(size_t)trow * HD + 32 + quad * 8];
    }
    #pragma unroll
    for (int ms = 0; ms < 3; ms++) {
        int m = ms * 16 + l16;
        int n = isW ? m * GRD + g : g * GRD + m;
        bf16x8 a0 = *(const bf16x8*)&Qb[(size_t)(h * NTOK + n) * HD + quad * 8];
        bf16x8 a1 = *(const bf16x8*)&Qb[(size_t)(h * NTOK + n) * HD + 32 + quad * 8];
        #pragma unroll
        for (int ct = 0; ct < 3; ct++) {
            acc[ms][ct] = __builtin_amdgcn_mfma_f32_16x16x32_bf16(a0, bfr[ct][0], acc[ms][ct], 0, 0, 0);
            acc[ms][ct] = __builtin_amdgcn_mfma_f32_16x16x32_bf16(a1, bfr[ct][1], acc[ms][ct], 0, 0, 0);
        }
    }
    #pragma unroll
    for (int ms = 0; ms < 3; ms++) {
        #pragma unroll
        for (int ct = 0; ct < 3; ct++) {
            #pragma unroll
            for (int r = 0; r < 4; r++) {
                int m = ms * 16 + quad * 4 + r;
                int n = isW ? m * GRD + g : g * GRD + m;
                int col = ct * 16 + l16;
                float val = acc[ms][ct][r] * LOG2E;
                if (isW)
                    relWb[(size_t)(h * NTOK + n) * GRD + col] = f2bf(val);
                else
                    relH[(size_t)(h * NTOK + n) * GRD + col] = val;
            }
        }
    }
}

// ---------------------------------------------------------------------------
// Flash attention, split-K. Block = (128 q-rows, head, chunk of 768 keys).
// Grid x = h*3+chunk -> 648 blocks <= 768 capacity (3 blk/CU): single-phase.
// Coalesced uint4 reg-prefetch -> stride-68 LDS; S^T compute. relW direct
// from global as bf16 uint2 pairs (prefetched per kt). rhs: 16-col slice,
// stride 18 (conflict-free). __launch_bounds__(256,3): budget 170 total,
// R12-verified 84 arch + AGPR, no spill.
// ---------------------------------------------------------------------------
__global__ __launch_bounds__(256, 3) void k_attn(
    const ushort_t* __restrict__ Qb, const ushort_t* __restrict__ Kb,
    const ushort_t* __restrict__ Vtb, const float* __restrict__ relH,
    const ushort_t* __restrict__ relWb, float* __restrict__ Opart,
    float* __restrict__ Lpart) {
    int h = blockIdx.x / CHUNKS, chunk = blockIdx.x - h * CHUNKS;
    int qt = blockIdx.y;
    int tid = threadIdx.x;
    int wave = tid >> 6, lane = tid & 63, quad = lane >> 4, l16 = lane & 15;
    int qbase = qt * 128;
    int kbase = chunk * KEYS_PER_CHUNK;

    __shared__ __align__(16) ushort_t Ks[64 * 68];
    __shared__ __align__(16) ushort_t Vs[64 * 68];
    __shared__ __align__(16) ushort_t Ps[4][32 * 68];
    __shared__ __align__(16) ushort_t rhs[128 * 18];

    for (int i = tid; i < 128 * 16; i += 256) {
        int r = i >> 4, c = i & 15;
        rhs[r * 18 + c] = f2bf(relH[(size_t)(h * NTOK + qbase + r) * GRD + chunk * 16 + c]);
    }

    bf16x8 qf[2][2];
    #pragma unroll
    for (int s = 0; s < 2; s++) {
        int qrow = qbase + wave * 32 + s * 16 + l16;
        qf[s][0] = *(const bf16x8*)&Qb[(size_t)(h * NTOK + qrow) * HD + quad * 8];
        qf[s][1] = *(const bf16x8*)&Qb[(size_t)(h * NTOK + qrow) * HD + 32 + quad * 8];
    }

    int r0 = tid >> 3, c0 = (tid & 7) * 8;
    const ushort_t* kg0 = Kb + (size_t)(h * NTOK + r0) * HD + c0;
    const ushort_t* kg1 = Kb + (size_t)(h * NTOK + r0 + 32) * HD + c0;
    const ushort_t* vg0 = Vtb + (size_t)(h * HD + r0) * NTOK + c0;
    const ushort_t* vg1 = Vtb + (size_t)(h * HD + r0 + 32) * NTOK + c0;
    int sk0 = r0 * 68 + c0, sk1 = sk0 + 32 * 68;

    // per-lane relW row pointers (rows owned by this lane across s=0,1)
    const ushort_t* rw0 = relWb + (size_t)(h * NTOK + qbase + wave * 32 + l16) * GRD;
    const ushort_t* rw1 = rw0 + (size_t)16 * GRD;

    float lacc[2] = {0.f, 0.f};
    f32x4 zero = {0.f, 0.f, 0.f, 0.f};
    f32x4 oacc[2][4];
    #pragma unroll
    for (int s = 0; s < 2; s++)
        #pragma unroll
        for (int cs = 0; cs < 4; cs++) oacc[s][cs] = zero;

    const float scale2 = 0.125f * LOG2E;

    uint4 rk0 = *(const uint4*)(kg0 + (size_t)kbase * HD);
    uint4 rk1 = *(const uint4*)(kg1 + (size_t)kbase * HD);
    uint4 rv0 = *(const uint4*)(vg0 + kbase);
    uint4 rv1 = *(const uint4*)(vg1 + kbase);

    for (int kt = 0; kt < KT_PER; kt++) {
        int kb = kbase + kt * 64;

        // prefetch this iteration's relW bias (8B per (s,ks)); issued before
        // the barrier pair so the L2 latency hides under K/V staging + S-MFMA
        uint2 rwv[2][4];
        #pragma unroll
        for (int ks = 0; ks < 4; ks++) {
            int kb4 = kb + ks * 16 + quad * 4;
            int kh = kb4 / 48;
            int kw0 = kb4 - kh * 48;
            rwv[0][ks] = *(const uint2*)(rw0 + kw0);
            rwv[1][ks] = *(const uint2*)(rw1 + kw0);
        }

        __syncthreads();
        *(uint4*)&Ks[sk0] = rk0;  *(uint4*)&Ks[sk1] = rk1;
        *(uint4*)&Vs[sk0] = rv0;  *(uint4*)&Vs[sk1] = rv1;
        __syncthreads();
        if (kt < KT_PER - 1) {
            int kbn = kb + 64;
            rk0 = *(const uint4*)(kg0 + (size_t)kbn * HD);
            rk1 = *(const uint4*)(kg1 + (size_t)kbn * HD);
            rv0 = *(const uint4*)(vg0 + kbn);
            rv1 = *(const uint4*)(vg1 + kbn);
        }

        #pragma unroll
        for (int ks = 0; ks < 4; ks++) {
            bf16x8 kf0 = *(const bf16x8*)&Ks[(ks * 16 + l16) * 68 + quad * 8];
            bf16x8 kf1 = *(const bf16x8*)&Ks[(ks * 16 + l16) * 68 + 32 + quad * 8];
            f32x4 st[2];
            #pragma unroll
            for (int s = 0; s < 2; s++) {
                f32x4 z = zero;
                z = __builtin_amdgcn_mfma_f32_16x16x32_bf16(kf0, qf[s][0], z, 0, 0, 0);
                z = __builtin_amdgcn_mfma_f32_16x16x32_bf16(kf1, qf[s][1], z, 0, 0, 0);
                st[s] = z;
            }
            int kb4 = kb + ks * 16 + quad * 4;
            int khl = kb4 / 48 - chunk * 16;
            #pragma unroll
            for (int s = 0; s < 2; s++) {
                int row = wave * 32 + s * 16 + l16;
                float rh = bf2f(rhs[row * 18 + khl]);
                uint2 u = rwv[s][ks];
                float p0 = __builtin_amdgcn_exp2f(st[s][0] * scale2 + rh + __uint_as_float(u.x << 16));
                float p1 = __builtin_amdgcn_exp2f(st[s][1] * scale2 + rh + __uint_as_float(u.x & 0xffff0000u));
                float p2 = __builtin_amdgcn_exp2f(st[s][2] * scale2 + rh + __uint_as_float(u.y << 16));
                float p3 = __builtin_amdgcn_exp2f(st[s][3] * scale2 + rh + __uint_as_float(u.y & 0xffff0000u));
                lacc[s] += (p0 + p1) + (p2 + p3);
                uint2 w;
                w.x = __builtin_amdgcn_perm(__float_as_uint(p1), __float_as_uint(p0), 0x07060302u);
                w.y = __builtin_amdgcn_perm(__float_as_uint(p3), __float_as_uint(p2), 0x07060302u);
                *(uint2*)&Ps[wave][(s * 16 + l16) * 68 + ks * 16 + quad * 4] = w;
            }
        }

        bf16x8 vf[4][2];
        #pragma unroll
        for (int cs = 0; cs < 4; cs++) {
            vf[cs][0] = *(const bf16x8*)&Vs[(cs * 16 + l16) * 68 + quad * 8];
            vf[cs][1] = *(const bf16x8*)&Vs[(cs * 16 + l16) * 68 + 32 + quad * 8];
        }
        #pragma unroll
        for (int s = 0; s < 2; s++) {
            bf16x8 pa0 = *(const bf16x8*)&Ps[wave][(s * 16 + l16) * 68 + quad * 8];
            bf16x8 pa1 = *(const bf16x8*)&Ps[wave][(s * 16 + l16) * 68 + 32 + quad * 8];
            #pragma unroll
            for (int cs = 0; cs < 4; cs++) {
                oacc[s][cs] = __builtin_amdgcn_mfma_f32_16x16x32_bf16(pa0, vf[cs][0], oacc[s][cs], 0, 0, 0);
                oacc[s][cs] = __builtin_amdgcn_mfma_f32_16x16x32_bf16(pa1, vf[cs][1], oacc[s][cs], 0, 0, 0);
            }
        }
    }

    #pragma unroll
    for (int s = 0; s < 2; s++) {
        float l = lacc[s];
        l += __shfl_xor(l, 16);
        l += __shfl_xor(l, 32);
        lacc[s] = l;
    }

    size_t obase = (size_t)(chunk * HEADS + h) * NTOK;
    #pragma unroll
    for (int s = 0; s < 2; s++) {
        #pragma unroll
        for (int cs = 0; cs < 4; cs++) {
            #pragma unroll
            for (int r = 0; r < 4; r++) {
                int row = qbase + wave * 32 + s * 16 + quad * 4 + r;
                Opart[(obase + row) * HD + cs * 16 + l16] = oacc[s][cs][r];
            }
        }
        if (quad == 0)
            Lpart[obase + qbase + wave * 32 + s * 16 + l16] = lacc[s];
    }
}

// ---------------------------------------------------------------------------
// Merge split-K partials: Ob = (sum_ch O) / (sum_ch l), bf16.
// ---------------------------------------------------------------------------
__global__ __launch_bounds__(256) void k_merge(const float* __restrict__ Opart,
                                               const float* __restrict__ Lpart,
                                               ushort_t* __restrict__ Ob) {
    int t = blockIdx.x * 256 + threadIdx.x;
    int e = t * 4;
    int c = e & (HD - 1);
    int row = (e >> 6) % NTOK;
    int h = e / (NTOK * HD);
    const int ostride = HEADS * NTOK * HD;
    float4 s = {0.f, 0.f, 0.f, 0.f};
    float l = 0.f;
    #pragma unroll
    for (int ch = 0; ch < CHUNKS; ch++) {
        float4 v = *(const float4*)&Opart[(size_t)ch * ostride + e];
        s.x += v.x; s.y += v.y; s.z += v.z; s.w += v.w;
        l += Lpart[(size_t)(ch * HEADS + h) * NTOK + row];
    }
    float inv = 1.0f / l;
    ushort4 o = make_ushort4(f2bf(s.x * inv), f2bf(s.y * inv),
                             f2bf(s.z * inv), f2bf(s.w * inv));
    *(ushort4*)&Ob[(size_t)row * DIM + h * HD + c] = o;
}

// ---------------------------------------------------------------------------
// Output projection: 128(M)x64(N) tiles -> 216 blocks, BK=32,
// global_load_lds DMA staging, 12 KB LDS. 2x2 waves: wave = 64 rows x 32 cols.
// ---------------------------------------------------------------------------
__global__ __launch_bounds__(256) void k_gemm_proj(
    const ushort_t* __restrict__ Ob, const ushort_t* __restrict__ WTp,
    const float* __restrict__ bp, float* __restrict__ out) {
    __shared__ __align__(16) ushort_t As[128 * 32];   // 8 KB
    __shared__ __align__(16) ushort_t Bs[64 * 32];    // 4 KB
    int tid = threadIdx.x;
    int wave = tid >> 6, lane = tid & 63, quad = lane >> 4, l16 = lane & 15;
    int wx = wave & 1, wy = wave >> 1;
    int nb = blockIdx.x * 64, mb = blockIdx.y * 128;

    f32x4 zero = {0.f, 0.f, 0.f, 0.f};
    f32x4 acc[4][2];
    #pragma unroll
    for (int i = 0; i < 4; i++)
        #pragma unroll
        for (int j = 0; j < 2; j++) acc[i][j] = zero;

    int rl = lane >> 2;
    int cl = (lane & 3) * 8;
    const ushort_t* gA = Ob + (size_t)(mb + wave * 32 + rl) * DIM + cl;
    const ushort_t* gB = WTp + (size_t)(nb + wave * 16 + rl) * DIM + cl;
    ushort_t* lA = &As[(wave * 32) * 32];
    ushort_t* lB = &Bs[(wave * 16) * 32];

    for (int k0 = 0; k0 < DIM; k0 += 32) {
        __syncthreads();
        gload_lds16(gA + k0,            lA);
        gload_lds16(gA + k0 + 16 * DIM, lA + 16 * 32);
        gload_lds16(gB + k0,            lB);
        __syncthreads();
        bf16x8 af[4], bf[2];
        #pragma unroll
        for (int i = 0; i < 4; i++)
            af[i] = *(const bf16x8*)&As[(wy * 64 + i * 16 + l16) * 32 + quad * 8];
        #pragma unroll
        for (int j = 0; j < 2; j++)
            bf[j] = *(const bf16x8*)&Bs[(wx * 32 + j * 16 + l16) * 32 + quad * 8];
        #pragma unroll
        for (int i = 0; i < 4; i++)
            #pragma unroll
            for (int j = 0; j < 2; j++)
                acc[i][j] = __builtin_amdgcn_mfma_f32_16x16x32_bf16(af[i], bf[j], acc[i][j], 0, 0, 0);
    }

    #pragma unroll
    for (int j = 0; j < 2; j++) {
        int col = nb + wx * 32 + j * 16 + l16;
        float bval = bp[col];
        #pragma unroll
        for (int i = 0; i < 4; i++) {
            #pragma unroll
            for (int r = 0; r < 4; r++) {
                int row = mb + wy * 64 + i * 16 + quad * 4 + r;
                out[(size_t)row * DIM + col] = acc[i][j][r] + bval;
            }
        }
    }
}

// ---------------------------------------------------------------------------
extern "C" void kernel_launch(void* const* d_in, const int* in_sizes, int n_in,
                              void* d_out, int out_size, void* d_ws, size_t ws_size,
                              hipStream_t stream) {
    const float* x   = (const float*)d_in[0];
    const float* Wq  = (const float*)d_in[1];
    const float* bq  = (const float*)d_in[2];
    const float* Wk  = (const float*)d_in[3];
    const float* bk  = (const float*)d_in[4];
    const float* Wv  = (const float*)d_in[5];
    const float* bv  = (const float*)d_in[6];
    const float* Wp  = (const float*)d_in[7];
    const float* bp  = (const float*)d_in[8];
    const float* rph = (const float*)d_in[9];
    const float* rpw = (const float*)d_in[10];
    const float* Aq  = (const float*)d_in[11];
    const float* Bq  = (const float*)d_in[12];
    const float* Ak  = (const float*)d_in[13];
    const float* Bk  = (const float*)d_in[14];
    const float* Av  = (const float*)d_in[15];
    const float* Bv  = (const float*)d_in[16];
    float* out = (float*)d_out;

    char* w = (char*)d_ws;
    size_t off = 0;
    auto carve = [&](size_t bytes) {
        char* p = w + off;
        off += (bytes + 255) & ~(size_t)255;
        return p;
    };
    ushort_t* xb    = (ushort_t*)carve((size_t)NTOK * DIM * 2);
    ushort_t* WT    = (ushort_t*)carve((size_t)4 * DIM * DIM * 2);
    ushort_t* Qb    = (ushort_t*)carve((size_t)HEADS * NTOK * HD * 2);
    ushort_t* Kb    = (ushort_t*)carve((size_t)HEADS * NTOK * HD * 2);
    ushort_t* Vtb   = (ushort_t*)carve((size_t)HEADS * HD * NTOK * 2);
    float*    relH  = (float*)carve((size_t)HEADS * NTOK * GRD * 4);
    ushort_t* relWb = (ushort_t*)carve((size_t)HEADS * NTOK * GRD * 2);
    ushort_t* Ob    = (ushort_t*)carve((size_t)NTOK * DIM * 2);
    float*    Opart = (float*)carve((size_t)CHUNKS * HEADS * NTOK * HD * 4);
    float*    Lpart = (float*)carve((size_t)CHUNKS * HEADS * NTOK * 4);
    ushort_t* rphb  = (ushort_t*)carve((size_t)(2 * GRD - 1) * HD * 2);
    ushort_t* rpwb  = (ushort_t*)carve((size_t)(2 * GRD - 1) * HD * 2);

    k_prep<<<dim3(2304), dim3(256), 0, stream>>>(
        x, xb, rph, rpw, rphb, rpwb,
        Wq, Wk, Wv, Wp, Aq, Bq, Ak, Bk, Av, Bv, WT);
    k_gemm_qkv<<<dim3(36, 18), dim3(256), 0, stream>>>(
        xb, WT, bq, bk, bv, Qb, Kb, Vtb);
    k_relmm<<<dim3(288), dim3(256), 0, stream>>>(
        Qb, rphb, rpwb, relH, relWb);
    k_attn<<<dim3(HEADS * CHUNKS, NTOK / 128), dim3(256), 0, stream>>>(
        Qb, Kb, Vtb, relH, relWb, Opart, Lpart);
    k_merge<<<dim3(HEADS * NTOK * HD / (256 * 4)), dim3(256), 0, stream>>>(
        Opart, Lpart, Ob);
    k_gemm_proj<<<dim3(12, 18), dim3(256), 0, stream>>>(
        Ob, WT + (size_t)3 * DIM * DIM, bp, out);
}